// Round 14
// baseline (373.604 us; speedup 1.0000x reference)
//
#include <hip/hip_runtime.h>
#include <cstdint>
#include <cstddef>

#define H_DIM 128
#define N_DOC 32000
#define N_TOPIC 800
#define N_WORD 80000
#define BATCH 16
#define VOCAB 15000
#define NODES_ALL 145600
#define EDGES_ALL 850000
#define NBLK_SCAN 143
#define N4_SCAN 36400
#define LDSW 136

typedef short bf16x8 __attribute__((ext_vector_type(8)));
typedef float f32x4 __attribute__((ext_vector_type(4)));
typedef float f32x2 __attribute__((ext_vector_type(2)));
typedef unsigned short u16;
typedef unsigned char u8;

static __device__ __forceinline__ u16 f2bf(float x) {
  unsigned u = __float_as_uint(x);
  u += 0x7fffu + ((u >> 16) & 1u);
  return (u16)(u >> 16);
}
static __device__ __forceinline__ float b2f(unsigned h) {
  return __uint_as_float(h << 16);
}
static __device__ __forceinline__ unsigned fenc(float f) {
  unsigned u = __float_as_uint(f);
  return (u & 0x80000000u) ? ~u : (u | 0x80000000u);
}
static __device__ __forceinline__ float fdec(unsigned k) {
  return (k & 0x80000000u) ? __uint_as_float(k ^ 0x80000000u) : __uint_as_float(~k);
}
static __device__ __forceinline__ int wave_iscan(int v, int lane) {
  #pragma unroll
  for (int d = 1; d < 64; d <<= 1) {
    int t = __shfl_up(v, d);
    if (lane >= d) v += t;
  }
  return v;
}
static __device__ __forceinline__ unsigned blend2(unsigned pr, unsigned bl, float aa) {
  float v0 = b2f(pr & 0xffffu) * aa + b2f(bl & 0xffffu) * (1.f - aa);
  float v1 = b2f(pr >> 16) * aa + b2f(bl >> 16) * (1.f - aa);
  return (unsigned)f2bf(v0) | ((unsigned)f2bf(v1) << 16);
}
template<bool HI>
static __device__ __forceinline__ f32x2 cvt8(int w) {
  return __builtin_amdgcn_cvt_pk_f32_fp8(w, HI);
}

// ======================= weight prep =======================
__global__ __launch_bounds__(256) void prep_kernel(
    const float* __restrict__ KW, const float* __restrict__ Kb,
    const float* __restrict__ QW, const float* __restrict__ Qb,
    const float* __restrict__ VW, const float* __restrict__ Vb,
    const float* __restrict__ AW, const float* __restrict__ Ab,
    const float* __restrict__ rel_att, const float* __restrict__ rel_msg,
    const float* __restrict__ adapt_w, const float* __restrict__ adapt_b,
    u16* __restrict__ bl_arena, float* __restrict__ bias_arena)
{
  const int wid = blockIdx.x >> 3, t = blockIdx.x & 7;
  int KS, Kreal, fold;
  const float *W, *b, *R = nullptr;
  float scale = 1.f;
  if (wid == 0) { KS = 10; Kreal = 300; fold = 0; W = adapt_w; b = adapt_b; }
  else {
    KS = 4; Kreal = 128;
    const int wl = wid - 1, li = wl / 14, j = wl % 14;
    const int dstnid[5] = {0, 1, 0, 1, 2};
    if (j < 4) {
      fold = 0;
      const float* Wb = (j < 2) ? KW : VW;
      const float* bb = (j < 2) ? Kb : Vb;
      const int nid = (j & 1) ? 2 : 1;
      W = Wb + ((size_t)li * 3 + nid) * 16384; b = bb + ((size_t)li * 3 + nid) * 128;
    } else if (j < 9) {
      fold = 1; const int r = j - 4; const int nid = dstnid[r];
      W = QW + ((size_t)li * 3 + nid) * 16384; b = Qb + ((size_t)li * 3 + nid) * 128;
      R = rel_att + ((size_t)li * 5 + r) * 4096;
    } else {
      fold = 3; const int r = j - 9; const int nid = dstnid[r];
      W = AW + ((size_t)li * 3 + nid) * 16384; b = Ab + ((size_t)li * 3 + nid) * 128;
      R = rel_msg + ((size_t)li * 5 + r) * 4096;
      scale = (r == 4) ? 1.f : 0.5f;
    }
  }
  u16* obl = (wid == 0) ? bl_arena : bl_arena + 40960 + (size_t)(wid - 1) * 16384;
  float* obias = bias_arena + wid * 128;

  const int nelem = KS * 512;
  for (int e = threadIdx.x; e < nelem; e += 256) {
    const int s = e >> 9, rem = e & 511, l = rem >> 3, jj = rem & 7;
    const int k = s * 32 + ((l >> 4) << 3) + jj;
    const int nn = t * 16 + (l & 15);
    float v = 0.f;
    if (k < Kreal) {
      if (fold == 0) v = W[(size_t)k * 128 + nn];
      else if (fold == 1) {
        const int h = nn >> 5, d = nn & 31;
        const float* Wr = W + (size_t)k * 128 + h * 32;
        const float* Rh = R + h * 1024;
        for (int f = 0; f < 32; ++f) v += Wr[f] * Rh[d * 32 + f];
      } else {
        const int h = k >> 5, dd = k & 31;
        const float* Rh = R + h * 1024 + dd * 32;
        const float* Wc = W + (size_t)h * 32 * 128 + nn;
        float sa = 0.f;
        for (int f = 0; f < 32; ++f) sa += Rh[f] * Wc[(size_t)f * 128];
        v = sa * scale;
      }
    }
    obl[(size_t)(t * KS + s) * 512 + rem] = f2bf(v);
  }
  if (t == 0 && threadIdx.x < 128) {
    const int nn = threadIdx.x;
    float v = 0.f;
    if (fold != 1) v = b[nn];
    else {
      const int h = nn >> 5, d = nn & 31;
      const float* Rh = R + h * 1024;
      for (int f = 0; f < 32; ++f) v += b[h * 32 + f] * Rh[d * 32 + f];
    }
    obias[nn] = v;
  }
}

// ======================= GEMM helpers =======================
// pack 32 bf16 (row rr, cols cs..cs+31 in LDS) into 8 fp8 words (4 chunks x 2 u32)
static __device__ __forceinline__ void kv_pack_half(
    const u16* lds16, int rr, int cs, unsigned* out)
{
  #pragma unroll
  for (int q2 = 0; q2 < 4; ++q2) {
    uint4 ld = *reinterpret_cast<const uint4*>(&lds16[rr * LDSW + cs + q2 * 8]);
    int t0 = __builtin_amdgcn_cvt_pk_fp8_f32(b2f(ld.x & 0xffffu), b2f(ld.x >> 16), 0, false);
    out[2 * q2] = (unsigned)__builtin_amdgcn_cvt_pk_fp8_f32(b2f(ld.y & 0xffffu), b2f(ld.y >> 16), t0, true);
    int t1 = __builtin_amdgcn_cvt_pk_fp8_f32(b2f(ld.z & 0xffffu), b2f(ld.z >> 16), 0, false);
    out[2 * q2 + 1] = (unsigned)__builtin_amdgcn_cvt_pk_fp8_f32(b2f(ld.w & 0xffffu), b2f(ld.w >> 16), t1, true);
  }
}

// combined 16B store per chunk: chunk j = k[j*8..+8] | v[j*8..+8]
static __device__ __forceinline__ void kv_write_full(
    const unsigned* kr, const unsigned* vr, u8* kv, size_t m, int cs)
{
  u8* Cp = kv + m * 256 + (cs >> 3) * 16;
  #pragma unroll
  for (int q2 = 0; q2 < 4; ++q2)
    *reinterpret_cast<uint4*>(Cp + q2 * 16) =
        make_uint4(kr[2 * q2], kr[2 * q2 + 1], vr[2 * q2], vr[2 * q2 + 1]);
}

static __device__ __forceinline__ void bf16_write_row(
    const u16* lds16, int rr, int cs, u16* C, size_t m)
{
  u16* Cp = C + m * 128 + cs;
  #pragma unroll
  for (int q2 = 0; q2 < 4; ++q2)
    *reinterpret_cast<uint4*>(Cp + q2 * 8) =
        *reinterpret_cast<const uint4*>(&lds16[rr * LDSW + cs + q2 * 8]);
}

#define GEMM_ACC(AV, BLP)                                                        \
  {                                                                              \
    const u16* Bp = (BLP) + (size_t)lane * 8;                                    \
    _Pragma("unroll")                                                            \
    for (int s = 0; s < 4; ++s) {                                                \
      _Pragma("unroll")                                                          \
      for (int t = 0; t < 8; ++t) {                                              \
        bf16x8 bfr = *reinterpret_cast<const bf16x8*>(Bp + (size_t)(t * 4 + s) * 512); \
        acc[t] = __builtin_amdgcn_mfma_f32_16x16x32_bf16(AV[s], bfr, acc[t], 0, 0, 0); \
      }                                                                          \
    }                                                                            \
  }

#define ACC_TO_LDS(BIAS)                                                         \
  {                                                                              \
    _Pragma("unroll")                                                            \
    for (int t = 0; t < 8; ++t) {                                                \
      const int col = t * 16 + (lane & 15);                                      \
      const float bb = (BIAS)[col];                                              \
      const int mr = w * 16 + g * 4;                                             \
      _Pragma("unroll")                                                          \
      for (int j = 0; j < 4; ++j)                                                \
        lds16[(mr + j) * LDSW + col] = f2bf(acc[t][j] + bb);                     \
    }                                                                            \
  }

static __device__ __forceinline__ float lds_qc_dot(
    const u16* lds16, int rr, int cs, const float* __restrict__ qc)
{
  float dot = 0.f;
  #pragma unroll
  for (int q2 = 0; q2 < 4; ++q2) {
    uint4 ld = *reinterpret_cast<const uint4*>(&lds16[rr * LDSW + cs + q2 * 8]);
    float4 qa = *reinterpret_cast<const float4*>(&qc[cs + q2 * 8]);
    float4 qb = *reinterpret_cast<const float4*>(&qc[cs + q2 * 8 + 4]);
    dot += b2f(ld.x & 0xffffu) * qa.x + b2f(ld.x >> 16) * qa.y
         + b2f(ld.y & 0xffffu) * qa.z + b2f(ld.y >> 16) * qa.w
         + b2f(ld.z & 0xffffu) * qb.x + b2f(ld.z >> 16) * qb.y
         + b2f(ld.w & 0xffffu) * qb.z + b2f(ld.w >> 16) * qb.w;
  }
  return dot;
}

static __device__ __forceinline__ void vp_write(
    const u16* lds16, int rr, int cs, float u_keep, u8* vp, size_t m)
{
  unsigned wpk[8];
  #pragma unroll
  for (int q2 = 0; q2 < 4; ++q2) {
    uint4 ld = *reinterpret_cast<const uint4*>(&lds16[rr * LDSW + cs + q2 * 8]);
    int t0 = __builtin_amdgcn_cvt_pk_fp8_f32(u_keep * b2f(ld.x & 0xffffu), u_keep * b2f(ld.x >> 16), 0, false);
    wpk[2 * q2] = (unsigned)__builtin_amdgcn_cvt_pk_fp8_f32(u_keep * b2f(ld.y & 0xffffu), u_keep * b2f(ld.y >> 16), t0, true);
    int t1 = __builtin_amdgcn_cvt_pk_fp8_f32(u_keep * b2f(ld.z & 0xffffu), u_keep * b2f(ld.z >> 16), 0, false);
    wpk[2 * q2 + 1] = (unsigned)__builtin_amdgcn_cvt_pk_fp8_f32(u_keep * b2f(ld.w & 0xffffu), u_keep * b2f(ld.w >> 16), t1, true);
  }
  *reinterpret_cast<uint4*>(vp + m * 128 + cs)      = make_uint4(wpk[0], wpk[1], wpk[2], wpk[3]);
  *reinterpret_cast<uint4*>(vp + m * 128 + cs + 16) = make_uint4(wpk[4], wpk[5], wpk[6], wpk[7]);
}

// ======================= fused adapt + L0 word projections (1 wave/block) =======================
__global__ __launch_bounds__(64) void adapt_l0w_kernel(
    const u16* __restrict__ wtab, const int* __restrict__ word_ids,
    const u16* __restrict__ BLa, const float* __restrict__ ba,
    const u16* __restrict__ BLk, const float* __restrict__ bk,
    const u16* __restrict__ BLv, const float* __restrict__ bv,
    const u16* __restrict__ BLq, const float* __restrict__ bq,
    const float* __restrict__ qc, const float* __restrict__ priw,
    u16* __restrict__ hw, u8* __restrict__ kv, u8* __restrict__ vp,
    float* __restrict__ uf, u16* __restrict__ qout, int n)
{
  __shared__ u16 lds16[16 * LDSW];
  const int lane = threadIdx.x;
  const int w = 0;
  int rl = blockIdx.x * 16 + (lane & 15);
  if (rl >= n) rl = n - 1;
  const int row = word_ids[rl];
  const int g = lane >> 4;

  bf16x8 a10[10];
  const u16* Ap = wtab + (size_t)row * 320 + g * 8;
  #pragma unroll
  for (int s = 0; s < 10; ++s) a10[s] = *reinterpret_cast<const bf16x8*>(Ap + s * 32);

  const int rr = lane >> 2, cs = (lane & 3) * 32;
  const int m = blockIdx.x * 16 + rr;

  f32x4 acc[8];
  #pragma unroll
  for (int t = 0; t < 8; ++t) acc[t] = (f32x4)0.f;
  {
    const u16* Bp = BLa + (size_t)lane * 8;
    #pragma unroll
    for (int s = 0; s < 10; ++s) {
      #pragma unroll
      for (int t = 0; t < 8; ++t) {
        bf16x8 bfr = *reinterpret_cast<const bf16x8*>(Bp + (size_t)(t * 10 + s) * 512);
        acc[t] = __builtin_amdgcn_mfma_f32_16x16x32_bf16(a10[s], bfr, acc[t], 0, 0, 0);
      }
    }
  }
  #pragma unroll
  for (int t = 0; t < 8; ++t) {
    const int col = t * 16 + (lane & 15);
    const float bb = ba[col];
    const int mr = g * 4;
    #pragma unroll
    for (int j = 0; j < 4; ++j)
      lds16[(mr + j) * LDSW + col] = f2bf(tanhf(acc[t][j] + bb));
  }
  if (m < n) bf16_write_row(lds16, rr, cs, hw, m);
  bf16x8 an[4];
  {
    const int rloc = lane & 15;
    #pragma unroll
    for (int s = 0; s < 4; ++s)
      an[s] = *reinterpret_cast<const bf16x8*>(&lds16[rloc * LDSW + s * 32 + g * 8]);
  }

  // k (pack to regs + u)
  #pragma unroll
  for (int t = 0; t < 8; ++t) acc[t] = (f32x4)0.f;
  GEMM_ACC(an, BLk)
  ACC_TO_LDS(bk)
  unsigned kreg[8];
  float u_keep = 0.f;
  {
    kv_pack_half(lds16, rr, cs, kreg);
    float dot = lds_qc_dot(lds16, rr, cs, qc);
    u_keep = __expf(dot * (priw[cs >> 5] * 0.17677669529663687f));
    if (m < n) uf[m * 4 + (cs >> 5)] = u_keep;
  }
  // v (pack + combined kv store + vp)
  #pragma unroll
  for (int t = 0; t < 8; ++t) acc[t] = (f32x4)0.f;
  GEMM_ACC(an, BLv)
  ACC_TO_LDS(bv)
  if (m < n) {
    unsigned vreg[8];
    kv_pack_half(lds16, rr, cs, vreg);
    kv_write_full(kreg, vreg, kv, m, cs);
    vp_write(lds16, rr, cs, u_keep, vp, m);
  }
  // q_ww
  #pragma unroll
  for (int t = 0; t < 8; ++t) acc[t] = (f32x4)0.f;
  GEMM_ACC(an, BLq)
  ACC_TO_LDS(bq)
  if (m < n) bf16_write_row(lds16, rr, cs, qout, m);
}

// ======================= L1 topic k/v GEMM (1 wave/block) =======================
__global__ __launch_bounds__(64) void gemm_kv_kernel(
    const u16* __restrict__ A,
    const u16* __restrict__ BLk, const float* __restrict__ bk,
    const u16* __restrict__ BLv, const float* __restrict__ bv,
    u8* __restrict__ kv, int n)
{
  __shared__ u16 lds16[16 * LDSW];
  const int lane = threadIdx.x;
  const int w = 0;
  int rl = blockIdx.x * 16 + (lane & 15);
  if (rl >= n) rl = n - 1;
  const int g = lane >> 4;
  bf16x8 a[4];
  const u16* Ap = A + (size_t)rl * 128 + g * 8;
  #pragma unroll
  for (int s = 0; s < 4; ++s) a[s] = *reinterpret_cast<const bf16x8*>(Ap + s * 32);
  const int rr = lane >> 2, cs = (lane & 3) * 32;
  const int m = blockIdx.x * 16 + rr;

  f32x4 acc[8];
  #pragma unroll
  for (int t = 0; t < 8; ++t) acc[t] = (f32x4)0.f;
  GEMM_ACC(a, BLk)
  ACC_TO_LDS(bk)
  unsigned kreg[8];
  kv_pack_half(lds16, rr, cs, kreg);

  #pragma unroll
  for (int t = 0; t < 8; ++t) acc[t] = (f32x4)0.f;
  GEMM_ACC(a, BLv)
  ACC_TO_LDS(bv)
  if (m < n) {
    unsigned vreg[8];
    kv_pack_half(lds16, rr, cs, vreg);
    kv_write_full(kreg, vreg, kv, m, cs);
  }
}

// ======================= L0 topic projections (1 wave/block) =======================
__global__ __launch_bounds__(64) void gemmN_l0t_kernel(
    const u16* __restrict__ A,
    const u16* __restrict__ BLk, const float* __restrict__ bk,
    const u16* __restrict__ BLv, const float* __restrict__ bv,
    const u16* __restrict__ BLq0, const float* __restrict__ bq0,
    const u16* __restrict__ BLq1, const float* __restrict__ bq1,
    const float* __restrict__ qc, const float* __restrict__ prit,
    u8* __restrict__ kv, u8* __restrict__ vp, float* __restrict__ uf,
    u16* __restrict__ q0, u16* __restrict__ q1, int n)
{
  __shared__ u16 lds16[16 * LDSW];
  const int lane = threadIdx.x;
  const int w = 0;
  int rl = blockIdx.x * 16 + (lane & 15);
  if (rl >= n) rl = n - 1;
  const int g = lane >> 4;
  bf16x8 a[4];
  const u16* Ap = A + (size_t)rl * 128 + g * 8;
  #pragma unroll
  for (int s = 0; s < 4; ++s) a[s] = *reinterpret_cast<const bf16x8*>(Ap + s * 32);
  const int rr = lane >> 2, cs = (lane & 3) * 32;
  const int m = blockIdx.x * 16 + rr;

  f32x4 acc[8];
  #pragma unroll
  for (int t = 0; t < 8; ++t) acc[t] = (f32x4)0.f;
  GEMM_ACC(a, BLk)
  ACC_TO_LDS(bk)
  unsigned kreg[8];
  float u_keep = 0.f;
  {
    kv_pack_half(lds16, rr, cs, kreg);
    float dot = lds_qc_dot(lds16, rr, cs, qc);
    u_keep = __expf(dot * (prit[cs >> 5] * 0.17677669529663687f));
    if (m < n) uf[m * 4 + (cs >> 5)] = u_keep;
  }
  #pragma unroll
  for (int t = 0; t < 8; ++t) acc[t] = (f32x4)0.f;
  GEMM_ACC(a, BLv)
  ACC_TO_LDS(bv)
  if (m < n) {
    unsigned vreg[8];
    kv_pack_half(lds16, rr, cs, vreg);
    kv_write_full(kreg, vreg, kv, m, cs);
    vp_write(lds16, rr, cs, u_keep, vp, m);
  }
  #pragma unroll
  for (int t = 0; t < 8; ++t) acc[t] = (f32x4)0.f;
  GEMM_ACC(a, BLq0)
  ACC_TO_LDS(bq0)
  if (m < n) bf16_write_row(lds16, rr, cs, q0, m);

  #pragma unroll
  for (int t = 0; t < 8; ++t) acc[t] = (f32x4)0.f;
  GEMM_ACC(a, BLq1)
  ACC_TO_LDS(bq1)
  if (m < n) bf16_write_row(lds16, rr, cs, q1, m);
}

// ======================= dual-A comb GEMM (topic L0, 1 wave/block) =======================
__global__ __launch_bounds__(64) void gemm2_kernel(
    const u16* __restrict__ A2, const u16* __restrict__ BL0, const u16* __restrict__ BL1,
    const float* __restrict__ bias, u16* __restrict__ C,
    const float* __restrict__ skipp, int n)
{
  __shared__ u16 lds16[16 * LDSW];
  const int lane = threadIdx.x;
  const int w = 0;
  int rl = blockIdx.x * 16 + (lane & 15);
  if (rl >= n) rl = n - 1;
  const int g = lane >> 4;

  bf16x8 a0[4], a1[4];
  const u16* Ap = A2 + (size_t)rl * 256 + g * 8;
  #pragma unroll
  for (int s = 0; s < 4; ++s) {
    a0[s] = *reinterpret_cast<const bf16x8*>(Ap + s * 32);
    a1[s] = *reinterpret_cast<const bf16x8*>(Ap + 128 + s * 32);
  }
  f32x4 acc[8];
  #pragma unroll
  for (int t = 0; t < 8; ++t) acc[t] = (f32x4)0.f;
  const u16* Bp0 = BL0 + (size_t)lane * 8;
  const u16* Bp1 = BL1 + (size_t)lane * 8;
  #pragma unroll
  for (int s = 0; s < 4; ++s) {
    #pragma unroll
    for (int t = 0; t < 8; ++t) {
      bf16x8 b0 = *reinterpret_cast<const bf16x8*>(Bp0 + (size_t)(t * 4 + s) * 512);
      acc[t] = __builtin_amdgcn_mfma_f32_16x16x32_bf16(a0[s], b0, acc[t], 0, 0, 0);
      bf16x8 b1 = *reinterpret_cast<const bf16x8*>(Bp1 + (size_t)(t * 4 + s) * 512);
      acc[t] = __builtin_amdgcn_mfma_f32_16x16x32_bf16(a1[s], b1, acc[t], 0, 0, 0);
    }
  }
  ACC_TO_LDS(bias)
  const int rr = lane >> 2, cs = (lane & 3) * 32;
  const int m = blockIdx.x * 16 + rr;
  if (m < n) {
    const float aa = 1.f / (1.f + __expf(-skipp[0]));
    #pragma unroll
    for (int q2 = 0; q2 < 4; ++q2) {
      uint4 pr = *reinterpret_cast<const uint4*>(&lds16[rr * LDSW + cs + q2 * 8]);
      uint4 blv = *reinterpret_cast<const uint4*>(C + (size_t)m * 128 + cs + q2 * 8);
      uint4 st;
      st.x = blend2(pr.x, blv.x, aa);
      st.y = blend2(pr.y, blv.y, aa);
      st.z = blend2(pr.z, blv.z, aa);
      st.w = blend2(pr.w, blv.w, aa);
      *reinterpret_cast<uint4*>(C + (size_t)m * 128 + cs + q2 * 8) = st;
    }
  }
}

// ======================= L1 doc comb + fused segmax readout (256 thr) =======================
__global__ __launch_bounds__(256) void comb_readout_kernel(
    const u16* __restrict__ A2, const u16* __restrict__ BL0, const u16* __restrict__ BL1,
    const float* __restrict__ bias, const u16* __restrict__ hdold,
    const float* __restrict__ skipp, const int* __restrict__ gid,
    unsigned* __restrict__ g, int n)
{
  __shared__ u16 lds16[64 * LDSW];
  const int tid = threadIdx.x, lane = tid & 63, w = tid >> 6;
  int rl = blockIdx.x * 64 + w * 16 + (lane & 15);
  if (rl >= n) rl = n - 1;
  const int gq = lane >> 4;

  bf16x8 a0[4], a1[4];
  const u16* Ap = A2 + (size_t)rl * 256 + gq * 8;
  #pragma unroll
  for (int s = 0; s < 4; ++s) {
    a0[s] = *reinterpret_cast<const bf16x8*>(Ap + s * 32);
    a1[s] = *reinterpret_cast<const bf16x8*>(Ap + 128 + s * 32);
  }
  f32x4 acc[8];
  #pragma unroll
  for (int t = 0; t < 8; ++t) acc[t] = (f32x4)0.f;
  {
    const u16* Bp0 = BL0 + (size_t)lane * 8;
    const u16* Bp1 = BL1 + (size_t)lane * 8;
    #pragma unroll
    for (int s = 0; s < 4; ++s) {
      #pragma unroll
      for (int t = 0; t < 8; ++t) {
        bf16x8 b0 = *reinterpret_cast<const bf16x8*>(Bp0 + (size_t)(t * 4 + s) * 512);
        acc[t] = __builtin_amdgcn_mfma_f32_16x16x32_bf16(a0[s], b0, acc[t], 0, 0, 0);
        bf16x8 b1 = *reinterpret_cast<const bf16x8*>(Bp1 + (size_t)(t * 4 + s) * 512);
        acc[t] = __builtin_amdgcn_mfma_f32_16x16x32_bf16(a1[s], b1, acc[t], 0, 0, 0);
      }
    }
  }
  #pragma unroll
  for (int t = 0; t < 8; ++t) {
    const int col = t * 16 + (lane & 15);
    const float bb = bias[col];
    const int mr = w * 16 + gq * 4;
    #pragma unroll
    for (int j = 0; j < 4; ++j)
      lds16[(mr + j) * LDSW + col] = f2bf(acc[t][j] + bb);
  }
  const int rr = w * 16 + (lane >> 2), cs = (lane & 3) * 32;
  const int m = blockIdx.x * 64 + rr;
  if (m < n) {
    const float aa = 1.f / (1.f + __expf(-skipp[0]));
    #pragma unroll
    for (int q2 = 0; q2 < 4; ++q2) {
      uint4 pr = *reinterpret_cast<const uint4*>(&lds16[rr * LDSW + cs + q2 * 8]);
      uint4 blv = *reinterpret_cast<const uint4*>(hdold + (size_t)m * 128 + cs + q2 * 8);
      uint4 st;
      st.x = blend2(pr.x, blv.x, aa);
      st.y = blend2(pr.y, blv.y, aa);
      st.z = blend2(pr.z, blv.z, aa);
      st.w = blend2(pr.w, blv.w, aa);
      *reinterpret_cast<uint4*>(&lds16[rr * LDSW + cs + q2 * 8]) = st;
    }
  }
  __syncthreads();
  if (tid < 128) {
    const int c = tid;
    const int rmax = min(64, n - blockIdx.x * 64);
    int cur = -1; float mx = 0.f;
    for (int r = 0; r < rmax; ++r) {
      int gg = gid[blockIdx.x * 64 + r];
      float v = b2f(lds16[r * LDSW + c]);
      if (gg != cur) {
        if (cur >= 0) atomicMax(&g[cur * 128 + c], fenc(mx));
        cur = gg; mx = v;
      } else {
        mx = fmaxf(mx, v);
      }
    }
    if (cur >= 0) atomicMax(&g[cur * 128 + c], fenc(mx));
  }
}

// ======================= fused comb_d(L0, blend=0) + L1 doc q projections (1 wave) =======================
__global__ __launch_bounds__(64) void comb_dq_kernel(
    const u16* __restrict__ A2, const u16* __restrict__ BL0, const u16* __restrict__ BL1,
    const float* __restrict__ bias, const float* __restrict__ skipp,
    const u16* __restrict__ BLq0, const float* __restrict__ bq0,
    const u16* __restrict__ BLq1, const float* __restrict__ bq1,
    u16* __restrict__ hd, u16* __restrict__ q0, u16* __restrict__ q1, int n)
{
  __shared__ u16 lds16[16 * LDSW];
  const int lane = threadIdx.x;
  const int w = 0;
  int rl = blockIdx.x * 16 + (lane & 15);
  if (rl >= n) rl = n - 1;
  const int g = lane >> 4;

  bf16x8 a0[4], a1[4];
  const u16* Ap = A2 + (size_t)rl * 256 + g * 8;
  #pragma unroll
  for (int s = 0; s < 4; ++s) {
    a0[s] = *reinterpret_cast<const bf16x8*>(Ap + s * 32);
    a1[s] = *reinterpret_cast<const bf16x8*>(Ap + 128 + s * 32);
  }
  f32x4 acc[8];
  #pragma unroll
  for (int t = 0; t < 8; ++t) acc[t] = (f32x4)0.f;
  {
    const u16* Bp0 = BL0 + (size_t)lane * 8;
    const u16* Bp1 = BL1 + (size_t)lane * 8;
    #pragma unroll
    for (int s = 0; s < 4; ++s) {
      #pragma unroll
      for (int t = 0; t < 8; ++t) {
        bf16x8 b0 = *reinterpret_cast<const bf16x8*>(Bp0 + (size_t)(t * 4 + s) * 512);
        acc[t] = __builtin_amdgcn_mfma_f32_16x16x32_bf16(a0[s], b0, acc[t], 0, 0, 0);
        bf16x8 b1 = *reinterpret_cast<const bf16x8*>(Bp1 + (size_t)(t * 4 + s) * 512);
        acc[t] = __builtin_amdgcn_mfma_f32_16x16x32_bf16(a1[s], b1, acc[t], 0, 0, 0);
      }
    }
  }
  const float aa = 1.f / (1.f + __expf(-skipp[0]));
  #pragma unroll
  for (int t = 0; t < 8; ++t) {
    const int col = t * 16 + (lane & 15);
    const float bb = bias[col];
    const int mr = g * 4;
    #pragma unroll
    for (int j = 0; j < 4; ++j)
      lds16[(mr + j) * LDSW + col] = f2bf((acc[t][j] + bb) * aa);
  }
  const int rr = lane >> 2, cs = (lane & 3) * 32;
  const int m = blockIdx.x * 16 + rr;
  if (m < n) bf16_write_row(lds16, rr, cs, hd, m);
  bf16x8 an[4];
  {
    const int rloc = lane & 15;
    #pragma unroll
    for (int s = 0; s < 4; ++s)
      an[s] = *reinterpret_cast<const bf16x8*>(&lds16[rloc * LDSW + s * 32 + g * 8]);
  }
  #pragma unroll
  for (int t = 0; t < 8; ++t) acc[t] = (f32x4)0.f;
  GEMM_ACC(an, BLq0)
  ACC_TO_LDS(bq0)
  if (m < n) bf16_write_row(lds16, rr, cs, q0, m);
  #pragma unroll
  for (int t = 0; t < 8; ++t) acc[t] = (f32x4)0.f;
  GEMM_ACC(an, BLq1)
  ACC_TO_LDS(bq1)
  if (m < n) bf16_write_row(lds16, rr, cs, q1, m);
}

// ======================= fused comb_w(L0) + L1 word k/v (1 wave) =======================
__global__ __launch_bounds__(64) void comb_kv_kernel(
    const u16* __restrict__ Aw, const u16* __restrict__ hwold,
    const u16* __restrict__ BLc, const float* __restrict__ bc,
    const u16* __restrict__ BLk, const float* __restrict__ bk,
    const u16* __restrict__ BLv, const float* __restrict__ bv,
    const float* __restrict__ skipp, u8* __restrict__ kv, int n)
{
  __shared__ u16 lds16[16 * LDSW];
  const int lane = threadIdx.x;
  const int w = 0;
  int rl = blockIdx.x * 16 + (lane & 15);
  if (rl >= n) rl = n - 1;
  const int g = lane >> 4;

  bf16x8 a[4];
  const u16* Ap = Aw + (size_t)rl * 128 + g * 8;
  #pragma unroll
  for (int s = 0; s < 4; ++s) a[s] = *reinterpret_cast<const bf16x8*>(Ap + s * 32);

  f32x4 acc[8];
  #pragma unroll
  for (int t = 0; t < 8; ++t) acc[t] = (f32x4)0.f;
  GEMM_ACC(a, BLc)
  ACC_TO_LDS(bc)
  const int rr = lane >> 2, cs = (lane & 3) * 32;
  const int m = blockIdx.x * 16 + rr;
  if (m < n) {
    const float aa = 1.f / (1.f + __expf(-skipp[0]));
    #pragma unroll
    for (int q2 = 0; q2 < 4; ++q2) {
      uint4 pr = *reinterpret_cast<const uint4*>(&lds16[rr * LDSW + cs + q2 * 8]);
      uint4 blv = *reinterpret_cast<const uint4*>(hwold + (size_t)m * 128 + cs + q2 * 8);
      uint4 st;
      st.x = blend2(pr.x, blv.x, aa);
      st.y = blend2(pr.y, blv.y, aa);
      st.z = blend2(pr.z, blv.z, aa);
      st.w = blend2(pr.w, blv.w, aa);
      *reinterpret_cast<uint4*>(&lds16[rr * LDSW + cs + q2 * 8]) = st;
    }
  }
  bf16x8 an[4];
  {
    const int rloc = lane & 15;
    #pragma unroll
    for (int s = 0; s < 4; ++s)
      an[s] = *reinterpret_cast<const bf16x8*>(&lds16[rloc * LDSW + s * 32 + g * 8]);
  }
  #pragma unroll
  for (int t = 0; t < 8; ++t) acc[t] = (f32x4)0.f;
  GEMM_ACC(an, BLk)
  ACC_TO_LDS(bk)
  unsigned kreg[8];
  kv_pack_half(lds16, rr, cs, kreg);
  #pragma unroll
  for (int t = 0; t < 8; ++t) acc[t] = (f32x4)0.f;
  GEMM_ACC(an, BLv)
  ACC_TO_LDS(bv)
  if (m < n) {
    unsigned vreg[8];
    kv_pack_half(lds16, rr, cs, vreg);
    kv_write_full(kreg, vreg, kv, m, cs);
  }
}

// ======================= misc small kernels =======================
__global__ void conv_wtab_kernel(const float* __restrict__ we, u16* __restrict__ wt) {
  int i = blockIdx.x * 256 + threadIdx.x;
  if (i < VOCAB * 320) {
    int r = i / 320, c = i - r * 320;
    wt[i] = (c < 300) ? f2bf(we[(size_t)r * 300 + c]) : (u16)0;
  }
}

__global__ void gather_topic_kernel(const float* __restrict__ emb, const int* __restrict__ ids,
                                    u16* __restrict__ out) {
  int i = blockIdx.x * 256 + threadIdx.x;
  if (i < N_TOPIC * 128) {
    int node = i >> 7, c = i & 127;
    out[i] = f2bf(emb[(size_t)ids[node] * 128 + c]);
  }
}

// ======================= CSR build =======================
__global__ void count_rank_kernel(const int* __restrict__ td, const int* __restrict__ wd,
                                  const int* __restrict__ tt, const int* __restrict__ wt,
                                  const int* __restrict__ ww, int* cnt, int* __restrict__ rank) {
  int i = blockIdx.x * 256 + threadIdx.x;
  if (i >= EDGES_ALL) return;
  int b;
  if (i < 80000)       b = td[i];
  else if (i < 330000) b = 32000 + wd[i - 80000];
  else if (i < 350000) b = 64000 + tt[i - 330000];
  else if (i < 450000) b = 64800 + wt[i - 350000];
  else                 b = 65600 + ww[i - 450000];
  rank[i] = atomicAdd(&cnt[b], 1);
}

__global__ void fill_rank_kernel(const int* __restrict__ td_s, const int* __restrict__ td_d,
                                 const int* __restrict__ wd_s, const int* __restrict__ wd_d,
                                 const int* __restrict__ tt_s, const int* __restrict__ tt_d,
                                 const int* __restrict__ wt_s, const int* __restrict__ wt_d,
                                 const int* __restrict__ ww_s, const int* __restrict__ ww_d,
                                 const int* __restrict__ offs, const int* __restrict__ rank,
                                 int* __restrict__ csrc) {
  int i = blockIdx.x * 256 + threadIdx.x;
  if (i >= EDGES_ALL) return;
  int b, s;
  if (i < 80000)       { b = td_d[i];                  s = td_s[i]; }
  else if (i < 330000) { b = 32000 + wd_d[i - 80000];  s = wd_s[i - 80000]; }
  else if (i < 350000) { b = 64000 + tt_d[i - 330000]; s = tt_s[i - 330000]; }
  else if (i < 450000) { b = 64800 + wt_d[i - 350000]; s = wt_s[i - 350000]; }
  else                 { b = 65600 + ww_d[i - 450000]; s = ww_s[i - 450000]; }
  csrc[offs[b] + rank[i]] = s;
}

__global__ __launch_bounds__(256) void scanA_kernel(const int* __restrict__ cnt, int* __restrict__ bsum) {
  const int tid = threadIdx.x, lane = tid & 63, wv = tid >> 6;
  const int i4 = blockIdx.x * 256 + tid;
  int4 v = make_int4(0, 0, 0, 0);
  if (i4 < N4_SCAN) v = reinterpret_cast<const int4*>(cnt)[i4];
  int s = v.x + v.y + v.z + v.w;
  #pragma unroll
  for (int d = 1; d < 64; d <<= 1) s += __shfl_xor(s, d);
  __shared__ int ws[4];
  if (lane == 0) ws[wv] = s;
  __syncthreads();
  if (tid == 0) bsum[blockIdx.x] = ws[0] + ws[1] + ws[2] + ws[3];
}

__global__ __launch_bounds__(256) void scanB_kernel(const int* __restrict__ bsum,
                                                    int* __restrict__ bpre, int* __restrict__ offs,
                                                    unsigned* __restrict__ g) {
  const int tid = threadIdx.x, lane = tid & 63, wv = tid >> 6;
  int v = (tid < NBLK_SCAN) ? bsum[tid] : 0;
  int incl = wave_iscan(v, lane);
  __shared__ int ws[4];
  if (lane == 63) ws[wv] = incl;
  __syncthreads();
  int pre = 0;
  for (int j = 0; j < 4; ++j) if (j < wv) pre += ws[j];
  incl += pre;
  if (tid < NBLK_SCAN) bpre[tid] = incl - v;
  if (tid == NBLK_SCAN - 1) offs[NODES_ALL] = incl;
  for (int i = tid; i < BATCH * H_DIM; i += 256) g[i] = 0x007FFFFFu;
}

__global__ __launch_bounds__(256) void scanC_kernel(const int* __restrict__ cnt,
                                                    const int* __restrict__ bpre,
                                                    int* __restrict__ offs) {
  const int tid = threadIdx.x, lane = tid & 63, wv = tid >> 6;
  const int i4 = blockIdx.x * 256 + tid;
  int4 v = make_int4(0, 0, 0, 0);
  if (i4 < N4_SCAN) v = reinterpret_cast<const int4*>(cnt)[i4];
  const int tsum = v.x + v.y + v.z + v.w;
  int incl = wave_iscan(tsum, lane);
  __shared__ int ws[4];
  if (lane == 63) ws[wv] = incl;
  __syncthreads();
  int pre = bpre[blockIdx.x];
  for (int j = 0; j < 4; ++j) if (j < wv) pre += ws[j];
  int o0 = pre + incl - tsum;
  if (i4 < N4_SCAN) {
    int4 ov = make_int4(o0, o0 + v.x, o0 + v.x + v.y, o0 + v.x + v.y + v.z);
    reinterpret_cast<int4*>(offs)[i4] = ov;
  }
}

// ======================= aggregation =======================
struct AggArgs {
  const u16 *q_td, *q_wd, *q_tt, *q_wt, *q_ww;
  const u8 *kv_t, *kv_w, *vp_t, *vp_w;
  const float *uf_t, *uf_w;
  const int *csrc, *offs;
  const float *pri;
  u16 *t2_d, *t2_t, *t_w;
};

static __device__ __forceinline__ void butterfly4(
    f32x2 acc0, f32x2 acc1, f32x2 acc2, f32x2 acc3, float ss,
    int lane, f32x2& red, float& ss_out)
{
  ss += __shfl_xor(ss, 16); ss += __shfl_xor(ss, 32);
  const bool h16 = (lane & 16) != 0, h32 = (lane & 32) != 0;
  f32x2 k0 = h16 ? acc2 : acc0;
  f32x2 k1 = h16 ? acc3 : acc1;
  f32x2 s0 = h16 ? acc0 : acc2;
  f32x2 s1 = h16 ? acc1 : acc3;
  k0[0] += __shfl_xor(s0[0], 16); k0[1] += __shfl_xor(s0[1], 16);
  k1[0] += __shfl_xor(s1[0], 16); k1[1] += __shfl_xor(s1[1], 16);
  f32x2 kk = h32 ? k1 : k0;
  f32x2 sd = h32 ? k0 : k1;
  kk[0] += __shfl_xor(sd[0], 32); kk[1] += __shfl_xor(sd[1], 32);
  red = kk; ss_out = ss;
}

static __device__ __forceinline__ void agg_core(
    const u16* __restrict__ q, const u8* __restrict__ kv,
    const int* __restrict__ offs, const int* __restrict__ csrc,
    const float* __restrict__ pri,
    int node, int grp, int stride, int sl, int lane,
    f32x2& red, float& ss_out)
{
  const int e0 = offs[node], e1 = offs[node + 1];
  f32x2 acc0 = (f32x2)0.f, acc1 = (f32x2)0.f, acc2 = (f32x2)0.f, acc3 = (f32x2)0.f;
  float ss = 0.f;
  if (e1 > e0) {
    const float prih = pri[sl >> 2] * 0.17677669529663687f;
    const bf16x8 qv = *reinterpret_cast<const bf16x8*>(q + (size_t)node * 128 + sl * 8);
    f32x2 q2[4];
    #pragma unroll
    for (int p = 0; p < 4; ++p) {
      f32x2 t; t[0] = b2f((u16)qv[2 * p]); t[1] = b2f((u16)qv[2 * p + 1]); q2[p] = t;
    }
    const int last = e1 - 1;
    for (int base = e0; base < e1; base += 2 * stride) {
      const int eA = base + grp, eB = base + stride + grp;
      const bool vA = eA < e1, vB = eB < e1;
      const int sA = csrc[vA ? eA : last];
      const int sB = csrc[vB ? eB : last];
      const uint4 cA = *reinterpret_cast<const uint4*>(kv + (size_t)sA * 256 + sl * 16);
      const uint4 cB = *reinterpret_cast<const uint4*>(kv + (size_t)sB * 256 + sl * 16);
      f32x2 dA = q2[0] * cvt8<false>((int)cA.x);
      dA += q2[1] * cvt8<true>((int)cA.x);
      dA += q2[2] * cvt8<false>((int)cA.y);
      dA += q2[3] * cvt8<true>((int)cA.y);
      f32x2 dB = q2[0] * cvt8<false>((int)cB.x);
      dB += q2[1] * cvt8<true>((int)cB.x);
      dB += q2[2] * cvt8<false>((int)cB.y);
      dB += q2[3] * cvt8<true>((int)cB.y);
      float dotA = dA[0] + dA[1];
      float dotB = dB[0] + dB[1];
      dotA += __shfl_xor(dotA, 1); dotA += __shfl_xor(dotA, 2);
      dotB += __shfl_xor(dotB, 1); dotB += __shfl_xor(dotB, 2);
      const float wA = vA ? __expf(dotA * prih) : 0.f;
      const float wB = vB ? __expf(dotB * prih) : 0.f;
      ss += wA + wB;
      f32x2 wA2; wA2[0] = wA; wA2[1] = wA;
      f32x2 wB2; wB2[0] = wB; wB2[1] = wB;
      acc0 += wA2 * cvt8<false>((int)cA.z);
      acc1 += wA2 * cvt8<true>((int)cA.z);
      acc2 += wA2 * cvt8<false>((int)cA.w);
      acc3 += wA2 * cvt8<true>((int)cA.w);
      acc0 += wB2 * cvt8<false>((int)cB.z);
      acc1 += wB2 * cvt8<true>((int)cB.z);
      acc2 += wB2 * cvt8<false>((int)cB.w);
      acc3 += wB2 * cvt8<true>((int)cB.w);
    }
  }
  butterfly4(acc0, acc1, acc2, acc3, ss, lane, red, ss_out);
}

static __device__ __forceinline__ void agg_docu(
    const u8* __restrict__ vp, const float* __restrict__ uf,
    const int* __restrict__ offs, const int* __restrict__ csrc,
    int node, int sub, int sl, int lane,
    f32x2& red, float& ss_out)
{
  const int e0 = offs[node], e1 = offs[node + 1];
  f32x2 acc0 = (f32x2)0.f, acc1 = (f32x2)0.f, acc2 = (f32x2)0.f, acc3 = (f32x2)0.f;
  float ss = 0.f;
  if (e1 > e0) {
    const int h = sl >> 2;
    const int last = e1 - 1;
    for (int base = e0; base < e1; base += 8) {
      const int eA = base + sub, eB = base + 4 + sub;
      const bool vA = eA < e1, vB = eB < e1;
      const int sA = csrc[vA ? eA : last];
      const int sB = csrc[vB ? eB : last];
      uint2 cA = *reinterpret_cast<const uint2*>(vp + (size_t)sA * 128 + sl * 8);
      uint2 cB = *reinterpret_cast<const uint2*>(vp + (size_t)sB * 128 + sl * 8);
      float uA = uf[sA * 4 + h];
      float uB = uf[sB * 4 + h];
      if (!vA) { cA = make_uint2(0u, 0u); uA = 0.f; }
      if (!vB) { cB = make_uint2(0u, 0u); uB = 0.f; }
      ss += uA + uB;
      acc0 += cvt8<false>((int)cA.x); acc1 += cvt8<true>((int)cA.x);
      acc2 += cvt8<false>((int)cA.y); acc3 += cvt8<true>((int)cA.y);
      acc0 += cvt8<false>((int)cB.x); acc1 += cvt8<true>((int)cB.x);
      acc2 += cvt8<false>((int)cB.y); acc3 += cvt8<true>((int)cB.y);
    }
  }
  butterfly4(acc0, acc1, acc2, acc3, ss, lane, red, ss_out);
}

static __device__ __forceinline__ int chbase_of(int lane) {
  return (lane & 15) * 8 + ((lane >> 4) & 1) * 4 + ((lane >> 5) & 1) * 2;
}

template<int DOCU>
__global__ __launch_bounds__(256) void agg_all_kernel(AggArgs A, int topic_n)
{
  __shared__ float lacc[4][128];
  __shared__ float lssA[4];
  const int tid = threadIdx.x, lane = tid & 63, wv = tid >> 6;
  const int sub = lane >> 4, sl = lane & 15;
  const int bid = blockIdx.x;
  const int chb = chbase_of(lane);
  f32x2 red; float ss;

  if (bid < topic_n) {
    const int node = bid;
    for (int r = 0; r < 2; ++r) {
      agg_core(r ? A.q_wt : A.q_tt, r ? A.kv_w : A.kv_t,
               A.offs + (r ? 64800 : 64000), A.csrc, A.pri + (r ? 12 : 4),
               node, wv * 4 + sub, 16, sl, lane, red, ss);
      lacc[wv][chb] = red[0]; lacc[wv][chb + 1] = red[1];
      if (lane == 0) lssA[wv] = ss;
      __syncthreads();
      if (tid < 128) {
        float a = lacc[0][tid] + lacc[1][tid] + lacc[2][tid] + lacc[3][tid];
        float st = lssA[0] + lssA[1] + lssA[2] + lssA[3];
        float inv = (st > 0.f) ? 1.f / st : 0.f;
        A.t2_t[(size_t)node * 256 + r * 128 + tid] = f2bf(a * inv);
      }
      __syncthreads();
    }
  } else if (bid < topic_n + 8000) {
    const int node = (bid - topic_n) * 4 + wv;
    if (DOCU) {
      agg_docu(A.vp_t, A.uf_t, A.offs + 0, A.csrc, node, sub, sl, lane, red, ss);
    } else {
      agg_core(A.q_td, A.kv_t, A.offs + 0, A.csrc, A.pri + 0, node, sub, 4, sl, lane, red, ss);
    }
    {
      float inv = (ss > 0.f) ? 1.f / ss : 0.f;
      unsigned pk = (unsigned)f2bf(red[0] * inv) | ((unsigned)f2bf(red[1] * inv) << 16);
      *reinterpret_cast<unsigned*>(A.t2_d + (size_t)node * 256 + chb) = pk;
    }
    if (DOCU) {
      agg_docu(A.vp_w, A.uf_w, A.offs + 32000, A.csrc, node, sub, sl, lane, red, ss);
    } else {
      agg_core(A.q_wd, A.kv_w, A.offs + 32000, A.csrc, A.pri + 8, node, sub, 4, sl, lane, red, ss);
    }
    {
      float inv = (ss > 0.f) ? 1.f / ss : 0.f;
      unsigned pk = (unsigned)f2bf(red[0] * inv) | ((unsigned)f2bf(red[1] * inv) << 16);
      *reinterpret_cast<unsigned*>(A.t2_d + (size_t)node * 256 + 128 + chb) = pk;
    }
  } else {
    const int node = (bid - topic_n - 8000) * 4 + wv;
    agg_core(A.q_ww, A.kv_w, A.offs + 65600, A.csrc, A.pri + 16, node, sub, 4, sl, lane, red, ss);
    float inv = (ss > 0.f) ? 1.f / ss : 0.f;
    unsigned pk = (unsigned)f2bf(red[0] * inv) | ((unsigned)f2bf(red[1] * inv) << 16);
    *reinterpret_cast<unsigned*>(A.t_w + (size_t)node * 128 + chb) = pk;
  }
}

// ======================= readout =======================
__global__ void final_kernel(const unsigned* __restrict__ g, const float* __restrict__ out_w,
                             const float* __restrict__ out_b, const float* __restrict__ y,
                             float* out) {
  int tid = threadIdx.x;
  int b = tid >> 4, seg = tid & 15;
  float p = 0.f;
  #pragma unroll
  for (int j = 0; j < 8; ++j) {
    int c = seg * 8 + j;
    p += fdec(g[b * 128 + c]) * out_w[c];
  }
  p += __shfl_xor(p, 1);
  p += __shfl_xor(p, 2);
  p += __shfl_xor(p, 4);
  p += __shfl_xor(p, 8);
  __shared__ float logits[BATCH];
  __shared__ float losses[BATCH];
  if (seg == 0) logits[b] = p + out_b[0];
  __syncthreads();
  if (tid < BATCH) {
    float l = logits[tid];
    out[1 + tid] = 1.f / (1.f + expf(-l));
    float ls_pos = (l > 0.f) ? -log1pf(expf(-l)) : l - log1pf(expf(l));
    float ls_neg = (l < 0.f) ? -log1pf(expf(l)) : -l - log1pf(expf(-l));
    losses[tid] = -(y[tid] * ls_pos + (1.f - y[tid]) * ls_neg);
  }
  __syncthreads();
  if (tid == 0) {
    float s = 0.f;
    for (int j = 0; j < BATCH; ++j) s += losses[j];
    out[0] = s / (float)BATCH;
  }
}

// ======================= host =======================
extern "C" void kernel_launch(void* const* d_in, const int* in_sizes, int n_in,
                              void* d_out, int out_size, void* d_ws, size_t ws_size,
                              hipStream_t stream)
{
  const float* word_embeds  = (const float*)d_in[0];
  const float* topic_embeds = (const float*)d_in[1];
  const float* KW  = (const float*)d_in[2];
  const float* Kb  = (const float*)d_in[3];
  const float* QW  = (const float*)d_in[4];
  const float* Qb  = (const float*)d_in[5];
  const float* VW  = (const float*)d_in[6];
  const float* Vb  = (const float*)d_in[7];
  const float* AW  = (const float*)d_in[8];
  const float* Ab  = (const float*)d_in[9];
  const float* rel_att = (const float*)d_in[10];
  const float* rel_msg = (const float*)d_in[11];
  const float* rel_pri = (const float*)d_in[12];
  const float* skip    = (const float*)d_in[13];
  const float* adapt_w = (const float*)d_in[14];
  const float* adapt_b = (const float*)d_in[15];
  const float* out_w   = (const float*)d_in[16];
  const float* out_b   = (const float*)d_in[17];
  const float* y_data  = (const float*)d_in[18];
  const int* word_ids  = (const int*)d_in[19];
  const int* topic_ids = (const int*)d_in[20];
  const int* doc_gid   = (const int*)d_in[21];
  const int* td_src = (const int*)d_in[22];
  const int* td_dst = (const int*)d_in[23];
  const int* tt_src = (const int*)d_in[24];
  const int* tt_dst = (const int*)d_in[25];
  const int* wd_src = (const int*)d_in[26];
  const int* wd_dst = (const int*)d_in[27];
  const int* wt_src = (const int*)d_in[28];
  const int* wt_dst = (const int*)d_in[29];
  const int* ww_src = (const int*)d_in[30];
  const int* ww_dst = (const int*)d_in[31];

  char* base = (char*)d_ws;
  size_t off_b = 0;
  auto alloc = [&](size_t bytes) -> char* {
    char* p = base + off_b;
    off_b = (off_b + bytes + 255) & ~(size_t)255;
    return p;
  };

  u16* wtab = (u16*)alloc((size_t)VOCAB * 320 * 2);
  u16* hw   = (u16*)alloc((size_t)N_WORD * 128 * 2);
  u16* hd   = (u16*)alloc((size_t)N_DOC * 128 * 2);
  u16* ht   = (u16*)alloc((size_t)N_TOPIC * 128 * 2);
  u8*  kv_w = (u8*)alloc((size_t)N_WORD * 256);
  u8*  kv_t = (u8*)alloc((size_t)N_TOPIC * 256);
  u8*  vp_w = (u8*)alloc((size_t)N_WORD * 128);
  u8*  vp_t = (u8*)alloc((size_t)N_TOPIC * 128);
  float* uf_w = (float*)alloc((size_t)N_WORD * 4 * 4);
  float* uf_t = (float*)alloc((size_t)N_TOPIC * 4 * 4);
  u16* q_td = (u16*)alloc((size_t)N_DOC * 128 * 2);
  u16* q_wd = (u16*)alloc((size_t)N_DOC * 128 * 2);
  u16* q_tt = (u16*)alloc((size_t)N_TOPIC * 128 * 2);
  u16* q_wt = (u16*)alloc((size_t)N_TOPIC * 128 * 2);
  u16* q_ww = (u16*)alloc((size_t)N_WORD * 128 * 2);
  u16* t2_d = (u16*)alloc((size_t)N_DOC * 256 * 2);
  u16* t2_t = (u16*)alloc((size_t)N_TOPIC * 256 * 2);
  u16* t_w  = (u16*)alloc((size_t)N_WORD * 128 * 2);
  unsigned* g = (unsigned*)alloc((size_t)BATCH * 128 * 4);

  int* cnt_all  = (int*)alloc((size_t)NODES_ALL * 4);
  int* offs_all = (int*)alloc(((size_t)NODES_ALL + 1) * 4);
  int* csrc_all = (int*)alloc((size_t)EDGES_ALL * 4);
  int* rank_all = (int*)alloc((size_t)EDGES_ALL * 4);
  int* bsum     = (int*)alloc((size_t)NBLK_SCAN * 4);
  int* bpre     = (int*)alloc((size_t)NBLK_SCAN * 4);

  u16* blw        = (u16*)alloc((size_t)(40960 + 28 * 16384) * 2);
  float* bias_are = (float*)alloc((size_t)29 * 128 * 4);

  auto BLp = [&](int wid) -> const u16* {
    return (wid == 0) ? blw : blw + 40960 + (size_t)(wid - 1) * 16384;
  };
  auto BIp = [&](int wid) -> const float* { return bias_are + wid * 128; };
  auto WID = [&](int li, int j) { return 1 + li * 14 + j; };

  // ---- prep ----
  prep_kernel<<<29 * 8, 256, 0, stream>>>(KW, Kb, QW, Qb, VW, Vb, AW, Ab,
                                          rel_att, rel_msg, adapt_w, adapt_b, blw, bias_are);
  conv_wtab_kernel<<<(VOCAB * 320 + 255) / 256, 256, 0, stream>>>(word_embeds, wtab);
  gather_topic_kernel<<<(N_TOPIC * 128 + 255) / 256, 256, 0, stream>>>(topic_embeds, topic_ids, ht);

  hipMemsetAsync(cnt_all, 0, (size_t)NODES_ALL * 4, stream);
  count_rank_kernel<<<(EDGES_ALL + 255) / 256, 256, 0, stream>>>(
      td_dst, wd_dst, tt_dst, wt_dst, ww_dst, cnt_all, rank_all);
  scanA_kernel<<<NBLK_SCAN, 256, 0, stream>>>(cnt_all, bsum);
  scanB_kernel<<<1, 256, 0, stream>>>(bsum, bpre, offs_all, g);
  scanC_kernel<<<NBLK_SCAN, 256, 0, stream>>>(cnt_all, bpre, offs_all);
  fill_rank_kernel<<<(EDGES_ALL + 255) / 256, 256, 0, stream>>>(
      td_src, td_dst, wd_src, wd_dst, tt_src, tt_dst, wt_src, wt_dst, ww_src, ww_dst,
      offs_all, rank_all, csrc_all);

  const int GW16 = (N_WORD + 15) / 16, GD16 = (N_DOC + 15) / 16, GT16 = (N_TOPIC + 15) / 16;
  const int GD = (N_DOC + 63) / 64;

  // ================= layer 0 =================
  adapt_l0w_kernel<<<GW16, 64, 0, stream>>>(
      wtab, word_ids,
      BLp(0), BIp(0),
      BLp(WID(0, 1)), BIp(WID(0, 1)),
      BLp(WID(0, 3)), BIp(WID(0, 3)),
      BLp(WID(0, 8)), BIp(WID(0, 8)),
      BIp(WID(0, 6)), rel_pri + 8,
      hw, kv_w, vp_w, uf_w, q_ww, N_WORD);
  gemmN_l0t_kernel<<<GT16, 64, 0, stream>>>(
      ht,
      BLp(WID(0, 0)), BIp(WID(0, 0)),
      BLp(WID(0, 2)), BIp(WID(0, 2)),
      BLp(WID(0, 5)), BIp(WID(0, 5)),
      BLp(WID(0, 7)), BIp(WID(0, 7)),
      BIp(WID(0, 4)), rel_pri + 0,
      kv_t, vp_t, uf_t, q_tt, q_wt, N_TOPIC);

  AggArgs A0;
  A0.q_td = q_td; A0.q_wd = q_wd; A0.q_tt = q_tt; A0.q_wt = q_wt; A0.q_ww = q_ww;
  A0.kv_t = kv_t; A0.kv_w = kv_w; A0.vp_t = vp_t; A0.vp_w = vp_w;
  A0.uf_t = uf_t; A0.uf_w = uf_w;
  A0.csrc = csrc_all; A0.offs = offs_all;
  A0.pri = rel_pri;
  A0.t2_d = t2_d; A0.t2_t = t2_t; A0.t_w = t_w;
  agg_all_kernel<1><<<28800, 256, 0, stream>>>(A0, 800);

  comb_dq_kernel<<<GD16, 64, 0, stream>>>(
      t2_d, BLp(WID(0, 9)), BLp(WID(0, 11)), BIp(WID(0, 9)), skip + 0,
      BLp(WID(1, 4)), BIp(WID(1, 4)), BLp(WID(1, 6)), BIp(WID(1, 6)),
      hd, q_td, q_wd, N_DOC);
  gemm2_kernel<<<GT16, 64, 0, stream>>>(t2_t, BLp(WID(0, 10)), BLp(WID(0, 12)),
                                        BIp(WID(0, 10)), ht, skip + 1, N_TOPIC);
  comb_kv_kernel<<<GW16, 64, 0, stream>>>(
      t_w, hw, BLp(WID(0, 13)), BIp(WID(0, 13)),
      BLp(WID(1, 1)), BIp(WID(1, 1)), BLp(WID(1, 3)), BIp(WID(1, 3)),
      skip + 2, kv_w, N_WORD);

  // ================= layer 1 =================
  gemm_kv_kernel<<<GT16, 64, 0, stream>>>(
      ht, BLp(WID(1, 0)), BIp(WID(1, 0)), BLp(WID(1, 2)), BIp(WID(1, 2)), kv_t, N_TOPIC);

  AggArgs A1 = A0;
  A1.pri = rel_pri + 20;
  agg_all_kernel<0><<<8000, 256, 0, stream>>>(A1, 0);

  comb_readout_kernel<<<GD, 256, 0, stream>>>(
      t2_d, BLp(WID(1, 9)), BLp(WID(1, 11)), BIp(WID(1, 9)), hd,
      skip + 3, doc_gid, g, N_DOC);

  final_kernel<<<1, 256, 0, stream>>>(g, out_w, out_b, y_data, (float*)d_out);
}

// Round 15
// 335.368 us; speedup vs baseline: 1.1140x; 1.1140x over previous
//
#include <hip/hip_runtime.h>
#include <cstdint>
#include <cstddef>

#define H_DIM 128
#define N_DOC 32000
#define N_TOPIC 800
#define N_WORD 80000
#define BATCH 16
#define VOCAB 15000
#define NODES_ALL 145600
#define EDGES_ALL 850000
#define NBLK_SCAN 143
#define N4_SCAN 36400
#define LDSW 136

typedef short bf16x8 __attribute__((ext_vector_type(8)));
typedef float f32x4 __attribute__((ext_vector_type(4)));
typedef float f32x2 __attribute__((ext_vector_type(2)));
typedef unsigned short u16;
typedef unsigned char u8;

static __device__ __forceinline__ u16 f2bf(float x) {
  unsigned u = __float_as_uint(x);
  u += 0x7fffu + ((u >> 16) & 1u);
  return (u16)(u >> 16);
}
static __device__ __forceinline__ float b2f(unsigned h) {
  return __uint_as_float(h << 16);
}
static __device__ __forceinline__ unsigned fenc(float f) {
  unsigned u = __float_as_uint(f);
  return (u & 0x80000000u) ? ~u : (u | 0x80000000u);
}
static __device__ __forceinline__ float fdec(unsigned k) {
  return (k & 0x80000000u) ? __uint_as_float(k ^ 0x80000000u) : __uint_as_float(~k);
}
static __device__ __forceinline__ int wave_iscan(int v, int lane) {
  #pragma unroll
  for (int d = 1; d < 64; d <<= 1) {
    int t = __shfl_up(v, d);
    if (lane >= d) v += t;
  }
  return v;
}
static __device__ __forceinline__ unsigned blend2(unsigned pr, unsigned bl, float aa) {
  float v0 = b2f(pr & 0xffffu) * aa + b2f(bl & 0xffffu) * (1.f - aa);
  float v1 = b2f(pr >> 16) * aa + b2f(bl >> 16) * (1.f - aa);
  return (unsigned)f2bf(v0) | ((unsigned)f2bf(v1) << 16);
}
template<bool HI>
static __device__ __forceinline__ f32x2 cvt8(int w) {
  return __builtin_amdgcn_cvt_pk_f32_fp8(w, HI);
}

// ======================= weight prep =======================
__global__ __launch_bounds__(256) void prep_kernel(
    const float* __restrict__ KW, const float* __restrict__ Kb,
    const float* __restrict__ QW, const float* __restrict__ Qb,
    const float* __restrict__ VW, const float* __restrict__ Vb,
    const float* __restrict__ AW, const float* __restrict__ Ab,
    const float* __restrict__ rel_att, const float* __restrict__ rel_msg,
    const float* __restrict__ adapt_w, const float* __restrict__ adapt_b,
    u16* __restrict__ bl_arena, float* __restrict__ bias_arena)
{
  const int wid = blockIdx.x >> 3, t = blockIdx.x & 7;
  int KS, Kreal, fold;
  const float *W, *b, *R = nullptr;
  float scale = 1.f;
  if (wid == 0) { KS = 10; Kreal = 300; fold = 0; W = adapt_w; b = adapt_b; }
  else {
    KS = 4; Kreal = 128;
    const int wl = wid - 1, li = wl / 14, j = wl % 14;
    const int dstnid[5] = {0, 1, 0, 1, 2};
    if (j < 4) {
      fold = 0;
      const float* Wb = (j < 2) ? KW : VW;
      const float* bb = (j < 2) ? Kb : Vb;
      const int nid = (j & 1) ? 2 : 1;
      W = Wb + ((size_t)li * 3 + nid) * 16384; b = bb + ((size_t)li * 3 + nid) * 128;
    } else if (j < 9) {
      fold = 1; const int r = j - 4; const int nid = dstnid[r];
      W = QW + ((size_t)li * 3 + nid) * 16384; b = Qb + ((size_t)li * 3 + nid) * 128;
      R = rel_att + ((size_t)li * 5 + r) * 4096;
    } else {
      fold = 3; const int r = j - 9; const int nid = dstnid[r];
      W = AW + ((size_t)li * 3 + nid) * 16384; b = Ab + ((size_t)li * 3 + nid) * 128;
      R = rel_msg + ((size_t)li * 5 + r) * 4096;
      scale = (r == 4) ? 1.f : 0.5f;
    }
  }
  u16* obl = (wid == 0) ? bl_arena : bl_arena + 40960 + (size_t)(wid - 1) * 16384;
  float* obias = bias_arena + wid * 128;

  const int nelem = KS * 512;
  for (int e = threadIdx.x; e < nelem; e += 256) {
    const int s = e >> 9, rem = e & 511, l = rem >> 3, jj = rem & 7;
    const int k = s * 32 + ((l >> 4) << 3) + jj;
    const int nn = t * 16 + (l & 15);
    float v = 0.f;
    if (k < Kreal) {
      if (fold == 0) v = W[(size_t)k * 128 + nn];
      else if (fold == 1) {
        const int h = nn >> 5, d = nn & 31;
        const float* Wr = W + (size_t)k * 128 + h * 32;
        const float* Rh = R + h * 1024;
        for (int f = 0; f < 32; ++f) v += Wr[f] * Rh[d * 32 + f];
      } else {
        const int h = k >> 5, dd = k & 31;
        const float* Rh = R + h * 1024 + dd * 32;
        const float* Wc = W + (size_t)h * 32 * 128 + nn;
        float sa = 0.f;
        for (int f = 0; f < 32; ++f) sa += Rh[f] * Wc[(size_t)f * 128];
        v = sa * scale;
      }
    }
    obl[(size_t)(t * KS + s) * 512 + rem] = f2bf(v);
  }
  if (t == 0 && threadIdx.x < 128) {
    const int nn = threadIdx.x;
    float v = 0.f;
    if (fold != 1) v = b[nn];
    else {
      const int h = nn >> 5, d = nn & 31;
      const float* Rh = R + h * 1024;
      for (int f = 0; f < 32; ++f) v += b[h * 32 + f] * Rh[d * 32 + f];
    }
    obias[nn] = v;
  }
}

// ======================= GEMM helpers =======================
static __device__ __forceinline__ void kv_write_half(
    const u16* lds16, int rr, int cs, u8* kv, size_t m, int vhalf)
{
  u8* Cp = kv + m * 256 + (cs >> 3) * 16 + (vhalf ? 8 : 0);
  #pragma unroll
  for (int q2 = 0; q2 < 4; ++q2) {
    uint4 ld = *reinterpret_cast<const uint4*>(&lds16[rr * LDSW + cs + q2 * 8]);
    int t0 = __builtin_amdgcn_cvt_pk_fp8_f32(b2f(ld.x & 0xffffu), b2f(ld.x >> 16), 0, false);
    unsigned w0 = (unsigned)__builtin_amdgcn_cvt_pk_fp8_f32(b2f(ld.y & 0xffffu), b2f(ld.y >> 16), t0, true);
    int t1 = __builtin_amdgcn_cvt_pk_fp8_f32(b2f(ld.z & 0xffffu), b2f(ld.z >> 16), 0, false);
    unsigned w1 = (unsigned)__builtin_amdgcn_cvt_pk_fp8_f32(b2f(ld.w & 0xffffu), b2f(ld.w >> 16), t1, true);
    *reinterpret_cast<uint2*>(Cp + q2 * 16) = make_uint2(w0, w1);
  }
}

static __device__ __forceinline__ void bf16_write_row(
    const u16* lds16, int rr, int cs, u16* C, size_t m)
{
  u16* Cp = C + m * 128 + cs;
  #pragma unroll
  for (int q2 = 0; q2 < 4; ++q2)
    *reinterpret_cast<uint4*>(Cp + q2 * 8) =
        *reinterpret_cast<const uint4*>(&lds16[rr * LDSW + cs + q2 * 8]);
}

#define GEMM_ACC(AV, BLP)                                                        \
  {                                                                              \
    const u16* Bp = (BLP) + (size_t)lane * 8;                                    \
    _Pragma("unroll")                                                            \
    for (int s = 0; s < 4; ++s) {                                                \
      _Pragma("unroll")                                                          \
      for (int t = 0; t < 8; ++t) {                                              \
        bf16x8 bfr = *reinterpret_cast<const bf16x8*>(Bp + (size_t)(t * 4 + s) * 512); \
        acc[t] = __builtin_amdgcn_mfma_f32_16x16x32_bf16(AV[s], bfr, acc[t], 0, 0, 0); \
      }                                                                          \
    }                                                                            \
  }

#define ACC_TO_LDS(BIAS)                                                         \
  {                                                                              \
    _Pragma("unroll")                                                            \
    for (int t = 0; t < 8; ++t) {                                                \
      const int col = t * 16 + (lane & 15);                                      \
      const float bb = (BIAS)[col];                                              \
      const int mr = w * 16 + g * 4;                                             \
      _Pragma("unroll")                                                          \
      for (int j = 0; j < 4; ++j)                                                \
        lds16[(mr + j) * LDSW + col] = f2bf(acc[t][j] + bb);                     \
    }                                                                            \
  }

static __device__ __forceinline__ float lds_qc_dot(
    const u16* lds16, int rr, int cs, const float* __restrict__ qc)
{
  float dot = 0.f;
  #pragma unroll
  for (int q2 = 0; q2 < 4; ++q2) {
    uint4 ld = *reinterpret_cast<const uint4*>(&lds16[rr * LDSW + cs + q2 * 8]);
    float4 qa = *reinterpret_cast<const float4*>(&qc[cs + q2 * 8]);
    float4 qb = *reinterpret_cast<const float4*>(&qc[cs + q2 * 8 + 4]);
    dot += b2f(ld.x & 0xffffu) * qa.x + b2f(ld.x >> 16) * qa.y
         + b2f(ld.y & 0xffffu) * qa.z + b2f(ld.y >> 16) * qa.w
         + b2f(ld.z & 0xffffu) * qb.x + b2f(ld.z >> 16) * qb.y
         + b2f(ld.w & 0xffffu) * qb.z + b2f(ld.w >> 16) * qb.w;
  }
  return dot;
}

static __device__ __forceinline__ void vp_write(
    const u16* lds16, int rr, int cs, float u_keep, u8* vp, size_t m)
{
  unsigned wpk[8];
  #pragma unroll
  for (int q2 = 0; q2 < 4; ++q2) {
    uint4 ld = *reinterpret_cast<const uint4*>(&lds16[rr * LDSW + cs + q2 * 8]);
    int t0 = __builtin_amdgcn_cvt_pk_fp8_f32(u_keep * b2f(ld.x & 0xffffu), u_keep * b2f(ld.x >> 16), 0, false);
    wpk[2 * q2] = (unsigned)__builtin_amdgcn_cvt_pk_fp8_f32(u_keep * b2f(ld.y & 0xffffu), u_keep * b2f(ld.y >> 16), t0, true);
    int t1 = __builtin_amdgcn_cvt_pk_fp8_f32(u_keep * b2f(ld.z & 0xffffu), u_keep * b2f(ld.z >> 16), 0, false);
    wpk[2 * q2 + 1] = (unsigned)__builtin_amdgcn_cvt_pk_fp8_f32(u_keep * b2f(ld.w & 0xffffu), u_keep * b2f(ld.w >> 16), t1, true);
  }
  *reinterpret_cast<uint4*>(vp + m * 128 + cs)      = make_uint4(wpk[0], wpk[1], wpk[2], wpk[3]);
  *reinterpret_cast<uint4*>(vp + m * 128 + cs + 16) = make_uint4(wpk[4], wpk[5], wpk[6], wpk[7]);
}

// ======================= fused adapt + L0 word projections (1 wave/block) =======================
__global__ __launch_bounds__(64) void adapt_l0w_kernel(
    const u16* __restrict__ wtab, const int* __restrict__ word_ids,
    const u16* __restrict__ BLa, const float* __restrict__ ba,
    const u16* __restrict__ BLk, const float* __restrict__ bk,
    const u16* __restrict__ BLv, const float* __restrict__ bv,
    const u16* __restrict__ BLq, const float* __restrict__ bq,
    const float* __restrict__ qc, const float* __restrict__ priw,
    u16* __restrict__ hw, u8* __restrict__ kv, u8* __restrict__ vp,
    float* __restrict__ uf, u16* __restrict__ qout, int n)
{
  __shared__ u16 lds16[16 * LDSW];
  const int lane = threadIdx.x;
  const int w = 0;
  int rl = blockIdx.x * 16 + (lane & 15);
  if (rl >= n) rl = n - 1;
  const int row = word_ids[rl];
  const int g = lane >> 4;

  bf16x8 a10[10];
  const u16* Ap = wtab + (size_t)row * 320 + g * 8;
  #pragma unroll
  for (int s = 0; s < 10; ++s) a10[s] = *reinterpret_cast<const bf16x8*>(Ap + s * 32);

  const int rr = lane >> 2, cs = (lane & 3) * 32;
  const int m = blockIdx.x * 16 + rr;

  f32x4 acc[8];
  #pragma unroll
  for (int t = 0; t < 8; ++t) acc[t] = (f32x4)0.f;
  {
    const u16* Bp = BLa + (size_t)lane * 8;
    #pragma unroll
    for (int s = 0; s < 10; ++s) {
      #pragma unroll
      for (int t = 0; t < 8; ++t) {
        bf16x8 bfr = *reinterpret_cast<const bf16x8*>(Bp + (size_t)(t * 10 + s) * 512);
        acc[t] = __builtin_amdgcn_mfma_f32_16x16x32_bf16(a10[s], bfr, acc[t], 0, 0, 0);
      }
    }
  }
  #pragma unroll
  for (int t = 0; t < 8; ++t) {
    const int col = t * 16 + (lane & 15);
    const float bb = ba[col];
    const int mr = g * 4;
    #pragma unroll
    for (int j = 0; j < 4; ++j)
      lds16[(mr + j) * LDSW + col] = f2bf(tanhf(acc[t][j] + bb));
  }
  if (m < n) bf16_write_row(lds16, rr, cs, hw, m);
  bf16x8 an[4];
  {
    const int rloc = lane & 15;
    #pragma unroll
    for (int s = 0; s < 4; ++s)
      an[s] = *reinterpret_cast<const bf16x8*>(&lds16[rloc * LDSW + s * 32 + g * 8]);
  }

  // k (+u)
  #pragma unroll
  for (int t = 0; t < 8; ++t) acc[t] = (f32x4)0.f;
  GEMM_ACC(an, BLk)
  ACC_TO_LDS(bk)
  float u_keep = 0.f;
  if (m < n) {
    kv_write_half(lds16, rr, cs, kv, m, 0);
    float dot = lds_qc_dot(lds16, rr, cs, qc);
    u_keep = __expf(dot * (priw[cs >> 5] * 0.17677669529663687f));
    uf[m * 4 + (cs >> 5)] = u_keep;
  }
  // v (+vp)
  #pragma unroll
  for (int t = 0; t < 8; ++t) acc[t] = (f32x4)0.f;
  GEMM_ACC(an, BLv)
  ACC_TO_LDS(bv)
  if (m < n) {
    kv_write_half(lds16, rr, cs, kv, m, 1);
    vp_write(lds16, rr, cs, u_keep, vp, m);
  }
  // q_ww
  #pragma unroll
  for (int t = 0; t < 8; ++t) acc[t] = (f32x4)0.f;
  GEMM_ACC(an, BLq)
  ACC_TO_LDS(bq)
  if (m < n) bf16_write_row(lds16, rr, cs, qout, m);
}

// ======================= L1 topic k/v GEMM (1 wave/block) =======================
__global__ __launch_bounds__(64) void gemm_kv_kernel(
    const u16* __restrict__ A,
    const u16* __restrict__ BLk, const float* __restrict__ bk,
    const u16* __restrict__ BLv, const float* __restrict__ bv,
    u8* __restrict__ kv, int n)
{
  __shared__ u16 lds16[16 * LDSW];
  const int lane = threadIdx.x;
  const int w = 0;
  int rl = blockIdx.x * 16 + (lane & 15);
  if (rl >= n) rl = n - 1;
  const int g = lane >> 4;
  bf16x8 a[4];
  const u16* Ap = A + (size_t)rl * 128 + g * 8;
  #pragma unroll
  for (int s = 0; s < 4; ++s) a[s] = *reinterpret_cast<const bf16x8*>(Ap + s * 32);
  const int rr = lane >> 2, cs = (lane & 3) * 32;
  const int m = blockIdx.x * 16 + rr;

  f32x4 acc[8];
  #pragma unroll
  for (int t = 0; t < 8; ++t) acc[t] = (f32x4)0.f;
  GEMM_ACC(a, BLk)
  ACC_TO_LDS(bk)
  if (m < n) kv_write_half(lds16, rr, cs, kv, m, 0);

  #pragma unroll
  for (int t = 0; t < 8; ++t) acc[t] = (f32x4)0.f;
  GEMM_ACC(a, BLv)
  ACC_TO_LDS(bv)
  if (m < n) kv_write_half(lds16, rr, cs, kv, m, 1);
}

// ======================= L0 topic projections (1 wave/block) =======================
__global__ __launch_bounds__(64) void gemmN_l0t_kernel(
    const u16* __restrict__ A,
    const u16* __restrict__ BLk, const float* __restrict__ bk,
    const u16* __restrict__ BLv, const float* __restrict__ bv,
    const u16* __restrict__ BLq0, const float* __restrict__ bq0,
    const u16* __restrict__ BLq1, const float* __restrict__ bq1,
    const float* __restrict__ qc, const float* __restrict__ prit,
    u8* __restrict__ kv, u8* __restrict__ vp, float* __restrict__ uf,
    u16* __restrict__ q0, u16* __restrict__ q1, int n)
{
  __shared__ u16 lds16[16 * LDSW];
  const int lane = threadIdx.x;
  const int w = 0;
  int rl = blockIdx.x * 16 + (lane & 15);
  if (rl >= n) rl = n - 1;
  const int g = lane >> 4;
  bf16x8 a[4];
  const u16* Ap = A + (size_t)rl * 128 + g * 8;
  #pragma unroll
  for (int s = 0; s < 4; ++s) a[s] = *reinterpret_cast<const bf16x8*>(Ap + s * 32);
  const int rr = lane >> 2, cs = (lane & 3) * 32;
  const int m = blockIdx.x * 16 + rr;

  f32x4 acc[8];
  #pragma unroll
  for (int t = 0; t < 8; ++t) acc[t] = (f32x4)0.f;
  GEMM_ACC(a, BLk)
  ACC_TO_LDS(bk)
  float u_keep = 0.f;
  if (m < n) {
    kv_write_half(lds16, rr, cs, kv, m, 0);
    float dot = lds_qc_dot(lds16, rr, cs, qc);
    u_keep = __expf(dot * (prit[cs >> 5] * 0.17677669529663687f));
    uf[m * 4 + (cs >> 5)] = u_keep;
  }
  #pragma unroll
  for (int t = 0; t < 8; ++t) acc[t] = (f32x4)0.f;
  GEMM_ACC(a, BLv)
  ACC_TO_LDS(bv)
  if (m < n) {
    kv_write_half(lds16, rr, cs, kv, m, 1);
    vp_write(lds16, rr, cs, u_keep, vp, m);
  }
  #pragma unroll
  for (int t = 0; t < 8; ++t) acc[t] = (f32x4)0.f;
  GEMM_ACC(a, BLq0)
  ACC_TO_LDS(bq0)
  if (m < n) bf16_write_row(lds16, rr, cs, q0, m);

  #pragma unroll
  for (int t = 0; t < 8; ++t) acc[t] = (f32x4)0.f;
  GEMM_ACC(a, BLq1)
  ACC_TO_LDS(bq1)
  if (m < n) bf16_write_row(lds16, rr, cs, q1, m);
}

// ======================= dual-A comb GEMM (topic L0, 1 wave/block) =======================
__global__ __launch_bounds__(64) void gemm2_kernel(
    const u16* __restrict__ A2, const u16* __restrict__ BL0, const u16* __restrict__ BL1,
    const float* __restrict__ bias, u16* __restrict__ C,
    const float* __restrict__ skipp, int n)
{
  __shared__ u16 lds16[16 * LDSW];
  const int lane = threadIdx.x;
  const int w = 0;
  int rl = blockIdx.x * 16 + (lane & 15);
  if (rl >= n) rl = n - 1;
  const int g = lane >> 4;

  bf16x8 a0[4], a1[4];
  const u16* Ap = A2 + (size_t)rl * 256 + g * 8;
  #pragma unroll
  for (int s = 0; s < 4; ++s) {
    a0[s] = *reinterpret_cast<const bf16x8*>(Ap + s * 32);
    a1[s] = *reinterpret_cast<const bf16x8*>(Ap + 128 + s * 32);
  }
  f32x4 acc[8];
  #pragma unroll
  for (int t = 0; t < 8; ++t) acc[t] = (f32x4)0.f;
  const u16* Bp0 = BL0 + (size_t)lane * 8;
  const u16* Bp1 = BL1 + (size_t)lane * 8;
  #pragma unroll
  for (int s = 0; s < 4; ++s) {
    #pragma unroll
    for (int t = 0; t < 8; ++t) {
      bf16x8 b0 = *reinterpret_cast<const bf16x8*>(Bp0 + (size_t)(t * 4 + s) * 512);
      acc[t] = __builtin_amdgcn_mfma_f32_16x16x32_bf16(a0[s], b0, acc[t], 0, 0, 0);
      bf16x8 b1 = *reinterpret_cast<const bf16x8*>(Bp1 + (size_t)(t * 4 + s) * 512);
      acc[t] = __builtin_amdgcn_mfma_f32_16x16x32_bf16(a1[s], b1, acc[t], 0, 0, 0);
    }
  }
  ACC_TO_LDS(bias)
  const int rr = lane >> 2, cs = (lane & 3) * 32;
  const int m = blockIdx.x * 16 + rr;
  if (m < n) {
    const float aa = 1.f / (1.f + __expf(-skipp[0]));
    #pragma unroll
    for (int q2 = 0; q2 < 4; ++q2) {
      uint4 pr = *reinterpret_cast<const uint4*>(&lds16[rr * LDSW + cs + q2 * 8]);
      uint4 blv = *reinterpret_cast<const uint4*>(C + (size_t)m * 128 + cs + q2 * 8);
      uint4 st;
      st.x = blend2(pr.x, blv.x, aa);
      st.y = blend2(pr.y, blv.y, aa);
      st.z = blend2(pr.z, blv.z, aa);
      st.w = blend2(pr.w, blv.w, aa);
      *reinterpret_cast<uint4*>(C + (size_t)m * 128 + cs + q2 * 8) = st;
    }
  }
}

// ======================= L1 doc comb + fused segmax readout (256 thr) =======================
__global__ __launch_bounds__(256) void comb_readout_kernel(
    const u16* __restrict__ A2, const u16* __restrict__ BL0, const u16* __restrict__ BL1,
    const float* __restrict__ bias, const u16* __restrict__ hdold,
    const float* __restrict__ skipp, const int* __restrict__ gid,
    unsigned* __restrict__ g, int n)
{
  __shared__ u16 lds16[64 * LDSW];
  const int tid = threadIdx.x, lane = tid & 63, w = tid >> 6;
  int rl = blockIdx.x * 64 + w * 16 + (lane & 15);
  if (rl >= n) rl = n - 1;
  const int gq = lane >> 4;

  bf16x8 a0[4], a1[4];
  const u16* Ap = A2 + (size_t)rl * 256 + gq * 8;
  #pragma unroll
  for (int s = 0; s < 4; ++s) {
    a0[s] = *reinterpret_cast<const bf16x8*>(Ap + s * 32);
    a1[s] = *reinterpret_cast<const bf16x8*>(Ap + 128 + s * 32);
  }
  f32x4 acc[8];
  #pragma unroll
  for (int t = 0; t < 8; ++t) acc[t] = (f32x4)0.f;
  {
    const u16* Bp0 = BL0 + (size_t)lane * 8;
    const u16* Bp1 = BL1 + (size_t)lane * 8;
    #pragma unroll
    for (int s = 0; s < 4; ++s) {
      #pragma unroll
      for (int t = 0; t < 8; ++t) {
        bf16x8 b0 = *reinterpret_cast<const bf16x8*>(Bp0 + (size_t)(t * 4 + s) * 512);
        acc[t] = __builtin_amdgcn_mfma_f32_16x16x32_bf16(a0[s], b0, acc[t], 0, 0, 0);
        bf16x8 b1 = *reinterpret_cast<const bf16x8*>(Bp1 + (size_t)(t * 4 + s) * 512);
        acc[t] = __builtin_amdgcn_mfma_f32_16x16x32_bf16(a1[s], b1, acc[t], 0, 0, 0);
      }
    }
  }
  #pragma unroll
  for (int t = 0; t < 8; ++t) {
    const int col = t * 16 + (lane & 15);
    const float bb = bias[col];
    const int mr = w * 16 + gq * 4;
    #pragma unroll
    for (int j = 0; j < 4; ++j)
      lds16[(mr + j) * LDSW + col] = f2bf(acc[t][j] + bb);
  }
  const int rr = w * 16 + (lane >> 2), cs = (lane & 3) * 32;
  const int m = blockIdx.x * 64 + rr;
  if (m < n) {
    const float aa = 1.f / (1.f + __expf(-skipp[0]));
    #pragma unroll
    for (int q2 = 0; q2 < 4; ++q2) {
      uint4 pr = *reinterpret_cast<const uint4*>(&lds16[rr * LDSW + cs + q2 * 8]);
      uint4 blv = *reinterpret_cast<const uint4*>(hdold + (size_t)m * 128 + cs + q2 * 8);
      uint4 st;
      st.x = blend2(pr.x, blv.x, aa);
      st.y = blend2(pr.y, blv.y, aa);
      st.z = blend2(pr.z, blv.z, aa);
      st.w = blend2(pr.w, blv.w, aa);
      *reinterpret_cast<uint4*>(&lds16[rr * LDSW + cs + q2 * 8]) = st;
    }
  }
  __syncthreads();
  if (tid < 128) {
    const int c = tid;
    const int rmax = min(64, n - blockIdx.x * 64);
    int cur = -1; float mx = 0.f;
    for (int r = 0; r < rmax; ++r) {
      int gg = gid[blockIdx.x * 64 + r];
      float v = b2f(lds16[r * LDSW + c]);
      if (gg != cur) {
        if (cur >= 0) atomicMax(&g[cur * 128 + c], fenc(mx));
        cur = gg; mx = v;
      } else {
        mx = fmaxf(mx, v);
      }
    }
    if (cur >= 0) atomicMax(&g[cur * 128 + c], fenc(mx));
  }
}

// ======================= fused comb_d(L0, blend=0) + L1 doc q projections (1 wave) =======================
__global__ __launch_bounds__(64) void comb_dq_kernel(
    const u16* __restrict__ A2, const u16* __restrict__ BL0, const u16* __restrict__ BL1,
    const float* __restrict__ bias, const float* __restrict__ skipp,
    const u16* __restrict__ BLq0, const float* __restrict__ bq0,
    const u16* __restrict__ BLq1, const float* __restrict__ bq1,
    u16* __restrict__ hd, u16* __restrict__ q0, u16* __restrict__ q1, int n)
{
  __shared__ u16 lds16[16 * LDSW];
  const int lane = threadIdx.x;
  const int w = 0;
  int rl = blockIdx.x * 16 + (lane & 15);
  if (rl >= n) rl = n - 1;
  const int g = lane >> 4;

  bf16x8 a0[4], a1[4];
  const u16* Ap = A2 + (size_t)rl * 256 + g * 8;
  #pragma unroll
  for (int s = 0; s < 4; ++s) {
    a0[s] = *reinterpret_cast<const bf16x8*>(Ap + s * 32);
    a1[s] = *reinterpret_cast<const bf16x8*>(Ap + 128 + s * 32);
  }
  f32x4 acc[8];
  #pragma unroll
  for (int t = 0; t < 8; ++t) acc[t] = (f32x4)0.f;
  {
    const u16* Bp0 = BL0 + (size_t)lane * 8;
    const u16* Bp1 = BL1 + (size_t)lane * 8;
    #pragma unroll
    for (int s = 0; s < 4; ++s) {
      #pragma unroll
      for (int t = 0; t < 8; ++t) {
        bf16x8 b0 = *reinterpret_cast<const bf16x8*>(Bp0 + (size_t)(t * 4 + s) * 512);
        acc[t] = __builtin_amdgcn_mfma_f32_16x16x32_bf16(a0[s], b0, acc[t], 0, 0, 0);
        bf16x8 b1 = *reinterpret_cast<const bf16x8*>(Bp1 + (size_t)(t * 4 + s) * 512);
        acc[t] = __builtin_amdgcn_mfma_f32_16x16x32_bf16(a1[s], b1, acc[t], 0, 0, 0);
      }
    }
  }
  const float aa = 1.f / (1.f + __expf(-skipp[0]));
  #pragma unroll
  for (int t = 0; t < 8; ++t) {
    const int col = t * 16 + (lane & 15);
    const float bb = bias[col];
    const int mr = g * 4;
    #pragma unroll
    for (int j = 0; j < 4; ++j)
      lds16[(mr + j) * LDSW + col] = f2bf((acc[t][j] + bb) * aa);
  }
  const int rr = lane >> 2, cs = (lane & 3) * 32;
  const int m = blockIdx.x * 16 + rr;
  if (m < n) bf16_write_row(lds16, rr, cs, hd, m);
  bf16x8 an[4];
  {
    const int rloc = lane & 15;
    #pragma unroll
    for (int s = 0; s < 4; ++s)
      an[s] = *reinterpret_cast<const bf16x8*>(&lds16[rloc * LDSW + s * 32 + g * 8]);
  }
  #pragma unroll
  for (int t = 0; t < 8; ++t) acc[t] = (f32x4)0.f;
  GEMM_ACC(an, BLq0)
  ACC_TO_LDS(bq0)
  if (m < n) bf16_write_row(lds16, rr, cs, q0, m);
  #pragma unroll
  for (int t = 0; t < 8; ++t) acc[t] = (f32x4)0.f;
  GEMM_ACC(an, BLq1)
  ACC_TO_LDS(bq1)
  if (m < n) bf16_write_row(lds16, rr, cs, q1, m);
}

// ======================= fused comb_w(L0) + L1 word k/v (1 wave) =======================
__global__ __launch_bounds__(64) void comb_kv_kernel(
    const u16* __restrict__ Aw, const u16* __restrict__ hwold,
    const u16* __restrict__ BLc, const float* __restrict__ bc,
    const u16* __restrict__ BLk, const float* __restrict__ bk,
    const u16* __restrict__ BLv, const float* __restrict__ bv,
    const float* __restrict__ skipp, u8* __restrict__ kv, int n)
{
  __shared__ u16 lds16[16 * LDSW];
  const int lane = threadIdx.x;
  const int w = 0;
  int rl = blockIdx.x * 16 + (lane & 15);
  if (rl >= n) rl = n - 1;
  const int g = lane >> 4;

  bf16x8 a[4];
  const u16* Ap = Aw + (size_t)rl * 128 + g * 8;
  #pragma unroll
  for (int s = 0; s < 4; ++s) a[s] = *reinterpret_cast<const bf16x8*>(Ap + s * 32);

  f32x4 acc[8];
  #pragma unroll
  for (int t = 0; t < 8; ++t) acc[t] = (f32x4)0.f;
  GEMM_ACC(a, BLc)
  ACC_TO_LDS(bc)
  const int rr = lane >> 2, cs = (lane & 3) * 32;
  const int m = blockIdx.x * 16 + rr;
  if (m < n) {
    const float aa = 1.f / (1.f + __expf(-skipp[0]));
    #pragma unroll
    for (int q2 = 0; q2 < 4; ++q2) {
      uint4 pr = *reinterpret_cast<const uint4*>(&lds16[rr * LDSW + cs + q2 * 8]);
      uint4 blv = *reinterpret_cast<const uint4*>(hwold + (size_t)m * 128 + cs + q2 * 8);
      uint4 st;
      st.x = blend2(pr.x, blv.x, aa);
      st.y = blend2(pr.y, blv.y, aa);
      st.z = blend2(pr.z, blv.z, aa);
      st.w = blend2(pr.w, blv.w, aa);
      *reinterpret_cast<uint4*>(&lds16[rr * LDSW + cs + q2 * 8]) = st;
    }
  }
  bf16x8 an[4];
  {
    const int rloc = lane & 15;
    #pragma unroll
    for (int s = 0; s < 4; ++s)
      an[s] = *reinterpret_cast<const bf16x8*>(&lds16[rloc * LDSW + s * 32 + g * 8]);
  }
  #pragma unroll
  for (int t = 0; t < 8; ++t) acc[t] = (f32x4)0.f;
  GEMM_ACC(an, BLk)
  ACC_TO_LDS(bk)
  if (m < n) kv_write_half(lds16, rr, cs, kv, m, 0);
  #pragma unroll
  for (int t = 0; t < 8; ++t) acc[t] = (f32x4)0.f;
  GEMM_ACC(an, BLv)
  ACC_TO_LDS(bv)
  if (m < n) kv_write_half(lds16, rr, cs, kv, m, 1);
}

// ======================= misc small kernels =======================
__global__ void conv_wtab_kernel(const float* __restrict__ we, u16* __restrict__ wt) {
  int i = blockIdx.x * 256 + threadIdx.x;
  if (i < VOCAB * 320) {
    int r = i / 320, c = i - r * 320;
    wt[i] = (c < 300) ? f2bf(we[(size_t)r * 300 + c]) : (u16)0;
  }
}

__global__ void gather_topic_kernel(const float* __restrict__ emb, const int* __restrict__ ids,
                                    u16* __restrict__ out) {
  int i = blockIdx.x * 256 + threadIdx.x;
  if (i < N_TOPIC * 128) {
    int node = i >> 7, c = i & 127;
    out[i] = f2bf(emb[(size_t)ids[node] * 128 + c]);
  }
}

// ======================= CSR build =======================
__global__ void count_rank_kernel(const int* __restrict__ td, const int* __restrict__ wd,
                                  const int* __restrict__ tt, const int* __restrict__ wt,
                                  const int* __restrict__ ww, int* cnt, int* __restrict__ rank) {
  int i = blockIdx.x * 256 + threadIdx.x;
  if (i >= EDGES_ALL) return;
  int b;
  if (i < 80000)       b = td[i];
  else if (i < 330000) b = 32000 + wd[i - 80000];
  else if (i < 350000) b = 64000 + tt[i - 330000];
  else if (i < 450000) b = 64800 + wt[i - 350000];
  else                 b = 65600 + ww[i - 450000];
  rank[i] = atomicAdd(&cnt[b], 1);
}

__global__ void fill_rank_kernel(const int* __restrict__ td_s, const int* __restrict__ td_d,
                                 const int* __restrict__ wd_s, const int* __restrict__ wd_d,
                                 const int* __restrict__ tt_s, const int* __restrict__ tt_d,
                                 const int* __restrict__ wt_s, const int* __restrict__ wt_d,
                                 const int* __restrict__ ww_s, const int* __restrict__ ww_d,
                                 const int* __restrict__ offs, const int* __restrict__ rank,
                                 int* __restrict__ csrc) {
  int i = blockIdx.x * 256 + threadIdx.x;
  if (i >= EDGES_ALL) return;
  int b, s;
  if (i < 80000)       { b = td_d[i];                  s = td_s[i]; }
  else if (i < 330000) { b = 32000 + wd_d[i - 80000];  s = wd_s[i - 80000]; }
  else if (i < 350000) { b = 64000 + tt_d[i - 330000]; s = tt_s[i - 330000]; }
  else if (i < 450000) { b = 64800 + wt_d[i - 350000]; s = wt_s[i - 350000]; }
  else                 { b = 65600 + ww_d[i - 450000]; s = ww_s[i - 450000]; }
  csrc[offs[b] + rank[i]] = s;
}

__global__ __launch_bounds__(256) void scanA_kernel(const int* __restrict__ cnt, int* __restrict__ bsum) {
  const int tid = threadIdx.x, lane = tid & 63, wv = tid >> 6;
  const int i4 = blockIdx.x * 256 + tid;
  int4 v = make_int4(0, 0, 0, 0);
  if (i4 < N4_SCAN) v = reinterpret_cast<const int4*>(cnt)[i4];
  int s = v.x + v.y + v.z + v.w;
  #pragma unroll
  for (int d = 1; d < 64; d <<= 1) s += __shfl_xor(s, d);
  __shared__ int ws[4];
  if (lane == 0) ws[wv] = s;
  __syncthreads();
  if (tid == 0) bsum[blockIdx.x] = ws[0] + ws[1] + ws[2] + ws[3];
}

__global__ __launch_bounds__(256) void scanB_kernel(const int* __restrict__ bsum,
                                                    int* __restrict__ bpre, int* __restrict__ offs,
                                                    unsigned* __restrict__ g) {
  const int tid = threadIdx.x, lane = tid & 63, wv = tid >> 6;
  int v = (tid < NBLK_SCAN) ? bsum[tid] : 0;
  int incl = wave_iscan(v, lane);
  __shared__ int ws[4];
  if (lane == 63) ws[wv] = incl;
  __syncthreads();
  int pre = 0;
  for (int j = 0; j < 4; ++j) if (j < wv) pre += ws[j];
  incl += pre;
  if (tid < NBLK_SCAN) bpre[tid] = incl - v;
  if (tid == NBLK_SCAN - 1) offs[NODES_ALL] = incl;
  for (int i = tid; i < BATCH * H_DIM; i += 256) g[i] = 0x007FFFFFu;
}

__global__ __launch_bounds__(256) void scanC_kernel(const int* __restrict__ cnt,
                                                    const int* __restrict__ bpre,
                                                    int* __restrict__ offs) {
  const int tid = threadIdx.x, lane = tid & 63, wv = tid >> 6;
  const int i4 = blockIdx.x * 256 + tid;
  int4 v = make_int4(0, 0, 0, 0);
  if (i4 < N4_SCAN) v = reinterpret_cast<const int4*>(cnt)[i4];
  const int tsum = v.x + v.y + v.z + v.w;
  int incl = wave_iscan(tsum, lane);
  __shared__ int ws[4];
  if (lane == 63) ws[wv] = incl;
  __syncthreads();
  int pre = bpre[blockIdx.x];
  for (int j = 0; j < 4; ++j) if (j < wv) pre += ws[j];
  int o0 = pre + incl - tsum;
  if (i4 < N4_SCAN) {
    int4 ov = make_int4(o0, o0 + v.x, o0 + v.x + v.y, o0 + v.x + v.y + v.z);
    reinterpret_cast<int4*>(offs)[i4] = ov;
  }
}

// ======================= aggregation =======================
struct AggArgs {
  const u16 *q_td, *q_wd, *q_tt, *q_wt, *q_ww;
  const u8 *kv_t, *kv_w, *vp_t, *vp_w;
  const float *uf_t, *uf_w;
  const int *csrc, *offs;
  const float *pri;
  u16 *t2_d, *t2_t, *t_w;
};

static __device__ __forceinline__ void butterfly4(
    f32x2 acc0, f32x2 acc1, f32x2 acc2, f32x2 acc3, float ss,
    int lane, f32x2& red, float& ss_out)
{
  ss += __shfl_xor(ss, 16); ss += __shfl_xor(ss, 32);
  const bool h16 = (lane & 16) != 0, h32 = (lane & 32) != 0;
  f32x2 k0 = h16 ? acc2 : acc0;
  f32x2 k1 = h16 ? acc3 : acc1;
  f32x2 s0 = h16 ? acc0 : acc2;
  f32x2 s1 = h16 ? acc1 : acc3;
  k0[0] += __shfl_xor(s0[0], 16); k0[1] += __shfl_xor(s0[1], 16);
  k1[0] += __shfl_xor(s1[0], 16); k1[1] += __shfl_xor(s1[1], 16);
  f32x2 kk = h32 ? k1 : k0;
  f32x2 sd = h32 ? k0 : k1;
  kk[0] += __shfl_xor(sd[0], 32); kk[1] += __shfl_xor(sd[1], 32);
  red = kk; ss_out = ss;
}

static __device__ __forceinline__ void agg_core(
    const u16* __restrict__ q, const u8* __restrict__ kv,
    const int* __restrict__ offs, const int* __restrict__ csrc,
    const float* __restrict__ pri,
    int node, int grp, int stride, int sl, int lane,
    f32x2& red, float& ss_out)
{
  const int e0 = offs[node], e1 = offs[node + 1];
  f32x2 acc0 = (f32x2)0.f, acc1 = (f32x2)0.f, acc2 = (f32x2)0.f, acc3 = (f32x2)0.f;
  float ss = 0.f;
  if (e1 > e0) {
    const float prih = pri[sl >> 2] * 0.17677669529663687f;
    const bf16x8 qv = *reinterpret_cast<const bf16x8*>(q + (size_t)node * 128 + sl * 8);
    f32x2 q2[4];
    #pragma unroll
    for (int p = 0; p < 4; ++p) {
      f32x2 t; t[0] = b2f((u16)qv[2 * p]); t[1] = b2f((u16)qv[2 * p + 1]); q2[p] = t;
    }
    const int last = e1 - 1;
    for (int base = e0; base < e1; base += 2 * stride) {
      const int eA = base + grp, eB = base + stride + grp;
      const bool vA = eA < e1, vB = eB < e1;
      const int sA = csrc[vA ? eA : last];
      const int sB = csrc[vB ? eB : last];
      const uint4 cA = *reinterpret_cast<const uint4*>(kv + (size_t)sA * 256 + sl * 16);
      const uint4 cB = *reinterpret_cast<const uint4*>(kv + (size_t)sB * 256 + sl * 16);
      f32x2 dA = q2[0] * cvt8<false>((int)cA.x);
      dA += q2[1] * cvt8<true>((int)cA.x);
      dA += q2[2] * cvt8<false>((int)cA.y);
      dA += q2[3] * cvt8<true>((int)cA.y);
      f32x2 dB = q2[0] * cvt8<false>((int)cB.x);
      dB += q2[1] * cvt8<true>((int)cB.x);
      dB += q2[2] * cvt8<false>((int)cB.y);
      dB += q2[3] * cvt8<true>((int)cB.y);
      float dotA = dA[0] + dA[1];
      float dotB = dB[0] + dB[1];
      dotA += __shfl_xor(dotA, 1); dotA += __shfl_xor(dotA, 2);
      dotB += __shfl_xor(dotB, 1); dotB += __shfl_xor(dotB, 2);
      const float wA = vA ? __expf(dotA * prih) : 0.f;
      const float wB = vB ? __expf(dotB * prih) : 0.f;
      ss += wA + wB;
      f32x2 wA2; wA2[0] = wA; wA2[1] = wA;
      f32x2 wB2; wB2[0] = wB; wB2[1] = wB;
      acc0 += wA2 * cvt8<false>((int)cA.z);
      acc1 += wA2 * cvt8<true>((int)cA.z);
      acc2 += wA2 * cvt8<false>((int)cA.w);
      acc3 += wA2 * cvt8<true>((int)cA.w);
      acc0 += wB2 * cvt8<false>((int)cB.z);
      acc1 += wB2 * cvt8<true>((int)cB.z);
      acc2 += wB2 * cvt8<false>((int)cB.w);
      acc3 += wB2 * cvt8<true>((int)cB.w);
    }
  }
  butterfly4(acc0, acc1, acc2, acc3, ss, lane, red, ss_out);
}

static __device__ __forceinline__ void agg_docu(
    const u8* __restrict__ vp, const float* __restrict__ uf,
    const int* __restrict__ offs, const int* __restrict__ csrc,
    int node, int sub, int sl, int lane,
    f32x2& red, float& ss_out)
{
  const int e0 = offs[node], e1 = offs[node + 1];
  f32x2 acc0 = (f32x2)0.f, acc1 = (f32x2)0.f, acc2 = (f32x2)0.f, acc3 = (f32x2)0.f;
  float ss = 0.f;
  if (e1 > e0) {
    const int h = sl >> 2;
    const int last = e1 - 1;
    for (int base = e0; base < e1; base += 8) {
      const int eA = base + sub, eB = base + 4 + sub;
      const bool vA = eA < e1, vB = eB < e1;
      const int sA = csrc[vA ? eA : last];
      const int sB = csrc[vB ? eB : last];
      uint2 cA = *reinterpret_cast<const uint2*>(vp + (size_t)sA * 128 + sl * 8);
      uint2 cB = *reinterpret_cast<const uint2*>(vp + (size_t)sB * 128 + sl * 8);
      float uA = uf[sA * 4 + h];
      float uB = uf[sB * 4 + h];
      if (!vA) { cA = make_uint2(0u, 0u); uA = 0.f; }
      if (!vB) { cB = make_uint2(0u, 0u); uB = 0.f; }
      ss += uA + uB;
      acc0 += cvt8<false>((int)cA.x); acc1 += cvt8<true>((int)cA.x);
      acc2 += cvt8<false>((int)cA.y); acc3 += cvt8<true>((int)cA.y);
      acc0 += cvt8<false>((int)cB.x); acc1 += cvt8<true>((int)cB.x);
      acc2 += cvt8<false>((int)cB.y); acc3 += cvt8<true>((int)cB.y);
    }
  }
  butterfly4(acc0, acc1, acc2, acc3, ss, lane, red, ss_out);
}

static __device__ __forceinline__ int chbase_of(int lane) {
  return (lane & 15) * 8 + ((lane >> 4) & 1) * 4 + ((lane >> 5) & 1) * 2;
}

template<int DOCU>
__global__ __launch_bounds__(256) void agg_all_kernel(AggArgs A, int topic_n)
{
  __shared__ float lacc[4][128];
  __shared__ float lssA[4];
  const int tid = threadIdx.x, lane = tid & 63, wv = tid >> 6;
  const int sub = lane >> 4, sl = lane & 15;
  const int bid = blockIdx.x;
  const int chb = chbase_of(lane);
  f32x2 red; float ss;

  if (bid < topic_n) {
    const int node = bid;
    for (int r = 0; r < 2; ++r) {
      agg_core(r ? A.q_wt : A.q_tt, r ? A.kv_w : A.kv_t,
               A.offs + (r ? 64800 : 64000), A.csrc, A.pri + (r ? 12 : 4),
               node, wv * 4 + sub, 16, sl, lane, red, ss);
      lacc[wv][chb] = red[0]; lacc[wv][chb + 1] = red[1];
      if (lane == 0) lssA[wv] = ss;
      __syncthreads();
      if (tid < 128) {
        float a = lacc[0][tid] + lacc[1][tid] + lacc[2][tid] + lacc[3][tid];
        float st = lssA[0] + lssA[1] + lssA[2] + lssA[3];
        float inv = (st > 0.f) ? 1.f / st : 0.f;
        A.t2_t[(size_t)node * 256 + r * 128 + tid] = f2bf(a * inv);
      }
      __syncthreads();
    }
  } else if (bid < topic_n + 8000) {
    const int node = (bid - topic_n) * 4 + wv;
    if (DOCU) {
      agg_docu(A.vp_t, A.uf_t, A.offs + 0, A.csrc, node, sub, sl, lane, red, ss);
    } else {
      agg_core(A.q_td, A.kv_t, A.offs + 0, A.csrc, A.pri + 0, node, sub, 4, sl, lane, red, ss);
    }
    {
      float inv = (ss > 0.f) ? 1.f / ss : 0.f;
      unsigned pk = (unsigned)f2bf(red[0] * inv) | ((unsigned)f2bf(red[1] * inv) << 16);
      *reinterpret_cast<unsigned*>(A.t2_d + (size_t)node * 256 + chb) = pk;
    }
    if (DOCU) {
      agg_docu(A.vp_w, A.uf_w, A.offs + 32000, A.csrc, node, sub, sl, lane, red, ss);
    } else {
      agg_core(A.q_wd, A.kv_w, A.offs + 32000, A.csrc, A.pri + 8, node, sub, 4, sl, lane, red, ss);
    }
    {
      float inv = (ss > 0.f) ? 1.f / ss : 0.f;
      unsigned pk = (unsigned)f2bf(red[0] * inv) | ((unsigned)f2bf(red[1] * inv) << 16);
      *reinterpret_cast<unsigned*>(A.t2_d + (size_t)node * 256 + 128 + chb) = pk;
    }
  } else {
    const int node = (bid - topic_n - 8000) * 4 + wv;
    agg_core(A.q_ww, A.kv_w, A.offs + 65600, A.csrc, A.pri + 16, node, sub, 4, sl, lane, red, ss);
    float inv = (ss > 0.f) ? 1.f / ss : 0.f;
    unsigned pk = (unsigned)f2bf(red[0] * inv) | ((unsigned)f2bf(red[1] * inv) << 16);
    *reinterpret_cast<unsigned*>(A.t_w + (size_t)node * 128 + chb) = pk;
  }
}

// ======================= readout =======================
__global__ void final_kernel(const unsigned* __restrict__ g, const float* __restrict__ out_w,
                             const float* __restrict__ out_b, const float* __restrict__ y,
                             float* out) {
  int tid = threadIdx.x;
  int b = tid >> 4, seg = tid & 15;
  float p = 0.f;
  #pragma unroll
  for (int j = 0; j < 8; ++j) {
    int c = seg * 8 + j;
    p += fdec(g[b * 128 + c]) * out_w[c];
  }
  p += __shfl_xor(p, 1);
  p += __shfl_xor(p, 2);
  p += __shfl_xor(p, 4);
  p += __shfl_xor(p, 8);
  __shared__ float logits[BATCH];
  __shared__ float losses[BATCH];
  if (seg == 0) logits[b] = p + out_b[0];
  __syncthreads();
  if (tid < BATCH) {
    float l = logits[tid];
    out[1 + tid] = 1.f / (1.f + expf(-l));
    float ls_pos = (l > 0.f) ? -log1pf(expf(-l)) : l - log1pf(expf(l));
    float ls_neg = (l < 0.f) ? -log1pf(expf(l)) : -l - log1pf(expf(-l));
    losses[tid] = -(y[tid] * ls_pos + (1.f - y[tid]) * ls_neg);
  }
  __syncthreads();
  if (tid == 0) {
    float s = 0.f;
    for (int j = 0; j < BATCH; ++j) s += losses[j];
    out[0] = s / (float)BATCH;
  }
}

// ======================= host =======================
extern "C" void kernel_launch(void* const* d_in, const int* in_sizes, int n_in,
                              void* d_out, int out_size, void* d_ws, size_t ws_size,
                              hipStream_t stream)
{
  const float* word_embeds  = (const float*)d_in[0];
  const float* topic_embeds = (const float*)d_in[1];
  const float* KW  = (const float*)d_in[2];
  const float* Kb  = (const float*)d_in[3];
  const float* QW  = (const float*)d_in[4];
  const float* Qb  = (const float*)d_in[5];
  const float* VW  = (const float*)d_in[6];
  const float* Vb  = (const float*)d_in[7];
  const float* AW  = (const float*)d_in[8];
  const float* Ab  = (const float*)d_in[9];
  const float* rel_att = (const float*)d_in[10];
  const float* rel_msg = (const float*)d_in[11];
  const float* rel_pri = (const float*)d_in[12];
  const float* skip    = (const float*)d_in[13];
  const float* adapt_w = (const float*)d_in[14];
  const float* adapt_b = (const float*)d_in[15];
  const float* out_w   = (const float*)d_in[16];
  const float* out_b   = (const float*)d_in[17];
  const float* y_data  = (const float*)d_in[18];
  const int* word_ids  = (const int*)d_in[19];
  const int* topic_ids = (const int*)d_in[20];
  const int* doc_gid   = (const int*)d_in[21];
  const int* td_src = (const int*)d_in[22];
  const int* td_dst = (const int*)d_in[23];
  const int* tt_src = (const int*)d_in[24];
  const int* tt_dst = (const int*)d_in[25];
  const int* wd_src = (const int*)d_in[26];
  const int* wd_dst = (const int*)d_in[27];
  const int* wt_src = (const int*)d_in[28];
  const int* wt_dst = (const int*)d_in[29];
  const int* ww_src = (const int*)d_in[30];
  const int* ww_dst = (const int*)d_in[31];

  char* base = (char*)d_ws;
  size_t off_b = 0;
  auto alloc = [&](size_t bytes) -> char* {
    char* p = base + off_b;
    off_b = (off_b + bytes + 255) & ~(size_t)255;
    return p;
  };

  u16* wtab = (u16*)alloc((size_t)VOCAB * 320 * 2);
  u16* hw   = (u16*)alloc((size_t)N_WORD * 128 * 2);
  u16* hd   = (u16*)alloc((size_t)N_DOC * 128 * 2);
  u16* ht   = (u16*)alloc((size_t)N_TOPIC * 128 * 2);
  u8*  kv_w = (u8*)alloc((size_t)N_WORD * 256);
  u8*  kv_t = (u8*)alloc((size_t)N_TOPIC * 256);
  u8*  vp_w = (u8*)alloc((size_t)N_WORD * 128);
  u8*  vp_t = (u8*)alloc((size_t)N_TOPIC * 128);
  float* uf_w = (float*)alloc((size_t)N_WORD * 4 * 4);
  float* uf_t = (float*)alloc((size_t)N_TOPIC * 4 * 4);
  u16* q_td = (u16*)alloc((size_t)N_DOC * 128 * 2);
  u16* q_wd = (u16*)alloc((size_t)N_DOC * 128 * 2);
  u16* q_tt = (u16*)alloc((size_t)N_TOPIC * 128 * 2);
  u16* q_wt = (u16*)alloc((size_t)N_TOPIC * 128 * 2);
  u16* q_ww = (u16*)alloc((size_t)N_WORD * 128 * 2);
  u16* t2_d = (u16*)alloc((size_t)N_DOC * 256 * 2);
  u16* t2_t = (u16*)alloc((size_t)N_TOPIC * 256 * 2);
  u16* t_w  = (u16*)alloc((size_t)N_WORD * 128 * 2);
  unsigned* g = (unsigned*)alloc((size_t)BATCH * 128 * 4);

  int* cnt_all  = (int*)alloc((size_t)NODES_ALL * 4);
  int* offs_all = (int*)alloc(((size_t)NODES_ALL + 1) * 4);
  int* csrc_all = (int*)alloc((size_t)EDGES_ALL * 4);
  int* rank_all = (int*)alloc((size_t)EDGES_ALL * 4);
  int* bsum     = (int*)alloc((size_t)NBLK_SCAN * 4);
  int* bpre     = (int*)alloc((size_t)NBLK_SCAN * 4);

  u16* blw        = (u16*)alloc((size_t)(40960 + 28 * 16384) * 2);
  float* bias_are = (float*)alloc((size_t)29 * 128 * 4);

  auto BLp = [&](int wid) -> const u16* {
    return (wid == 0) ? blw : blw + 40960 + (size_t)(wid - 1) * 16384;
  };
  auto BIp = [&](int wid) -> const float* { return bias_are + wid * 128; };
  auto WID = [&](int li, int j) { return 1 + li * 14 + j; };

  // ---- prep ----
  prep_kernel<<<29 * 8, 256, 0, stream>>>(KW, Kb, QW, Qb, VW, Vb, AW, Ab,
                                          rel_att, rel_msg, adapt_w, adapt_b, blw, bias_are);
  conv_wtab_kernel<<<(VOCAB * 320 + 255) / 256, 256, 0, stream>>>(word_embeds, wtab);
  gather_topic_kernel<<<(N_TOPIC * 128 + 255) / 256, 256, 0, stream>>>(topic_embeds, topic_ids, ht);

  hipMemsetAsync(cnt_all, 0, (size_t)NODES_ALL * 4, stream);
  count_rank_kernel<<<(EDGES_ALL + 255) / 256, 256, 0, stream>>>(
      td_dst, wd_dst, tt_dst, wt_dst, ww_dst, cnt_all, rank_all);
  scanA_kernel<<<NBLK_SCAN, 256, 0, stream>>>(cnt_all, bsum);
  scanB_kernel<<<1, 256, 0, stream>>>(bsum, bpre, offs_all, g);
  scanC_kernel<<<NBLK_SCAN, 256, 0, stream>>>(cnt_all, bpre, offs_all);
  fill_rank_kernel<<<(EDGES_ALL + 255) / 256, 256, 0, stream>>>(
      td_src, td_dst, wd_src, wd_dst, tt_src, tt_dst, wt_src, wt_dst, ww_src, ww_dst,
      offs_all, rank_all, csrc_all);

  const int GW16 = (N_WORD + 15) / 16, GD16 = (N_DOC + 15) / 16, GT16 = (N_TOPIC + 15) / 16;
  const int GD = (N_DOC + 63) / 64;

  // ================= layer 0 =================
  adapt_l0w_kernel<<<GW16, 64, 0, stream>>>(
      wtab, word_ids,
      BLp(0), BIp(0),
      BLp(WID(0, 1)), BIp(WID(0, 1)),
      BLp(WID(0, 3)), BIp(WID(0, 3)),
      BLp(WID(0, 8)), BIp(WID(0, 8)),
      BIp(WID(0, 6)), rel_pri + 8,
      hw, kv_w, vp_w, uf_w, q_ww, N_WORD);
  gemmN_l0t_kernel<<<GT16, 64, 0, stream>>>(
      ht,
      BLp(WID(0, 0)), BIp(WID(0, 0)),
      BLp(WID(0, 2)), BIp(WID(0, 2)),
      BLp(WID(0, 5)), BIp(WID(0, 5)),
      BLp(WID(0, 7)), BIp(WID(0, 7)),
      BIp(WID(0, 4)), rel_pri + 0,
      kv_t, vp_t, uf_t, q_tt, q_wt, N_TOPIC);

  AggArgs A0;
  A0.q_td = q_td; A0.q_wd = q_wd; A0.q_tt = q_tt; A0.q_wt = q_wt; A0.q_ww = q_ww;
  A0.kv_t = kv_t; A0.kv_w = kv_w; A0.vp_t = vp_t; A0.vp_w = vp_w;
  A0.uf_t = uf_t; A0.uf_w = uf_w;
  A0.csrc = csrc_all; A0.offs = offs_all;
  A0.pri = rel_pri;
  A0.t2_d = t2_d; A0.t2_t = t2_t; A0.t_w = t_w;
  agg_all_kernel<1><<<28800, 256, 0, stream>>>(A0, 800);

  comb_dq_kernel<<<GD16, 64, 0, stream>>>(
      t2_d, BLp(WID(0, 9)), BLp(WID(0, 11)), BIp(WID(0, 9)), skip + 0,
      BLp(WID(1, 4)), BIp(WID(1, 4)), BLp(WID(1, 6)), BIp(WID(1, 6)),
      hd, q_td, q_wd, N_DOC);
  gemm2_kernel<<<GT16, 64, 0, stream>>>(t2_t, BLp(WID(0, 10)), BLp(WID(0, 12)),
                                        BIp(WID(0, 10)), ht, skip + 1, N_TOPIC);
  comb_kv_kernel<<<GW16, 64, 0, stream>>>(
      t_w, hw, BLp(WID(0, 13)), BIp(WID(0, 13)),
      BLp(WID(1, 1)), BIp(WID(1, 1)), BLp(WID(1, 3)), BIp(WID(1, 3)),
      skip + 2, kv_w, N_WORD);

  // ================= layer 1 =================
  gemm_kv_kernel<<<GT16, 64, 0, stream>>>(
      ht, BLp(WID(1, 0)), BIp(WID(1, 0)), BLp(WID(1, 2)), BIp(WID(1, 2)), kv_t, N_TOPIC);

  AggArgs A1 = A0;
  A1.pri = rel_pri + 20;
  agg_all_kernel<0><<<8000, 256, 0, stream>>>(A1, 0);

  comb_readout_kernel<<<GD, 256, 0, stream>>>(
      t2_d, BLp(WID(1, 9)), BLp(WID(1, 11)), BIp(WID(1, 9)), hd,
      skip + 3, doc_gid, g, N_DOC);

  final_kernel<<<1, 256, 0, stream>>>(g, out_w, out_b, y_data, (float*)d_out);
}